// Round 1
// baseline (2848.707 us; speedup 1.0000x reference)
//
#include <hip/hip_runtime.h>
#include <hip/hip_bf16.h>

// Dims
#define BB 256
#define LL 128
#define AA 39
#define BDD 10
#define KK 6
#define MM 256
#define FP 256
#define RR 3
#define TT 2

// ---------------- transpose: dst[i*O+o] = src[o*I+i] ----------------
__global__ __launch_bounds__(256) void k_transpose(const float* __restrict__ src,
                                                   float* __restrict__ dst, int O, int I) {
    int idx = blockIdx.x * 256 + threadIdx.x;
    if (idx >= O * I) return;
    int o = idx / I, i = idx - o * I;
    dst[i * O + o] = src[idx];
}

// ---------------- atom fc: pre = atom_list @ W.T + b ----------------
// writes afv[0] = pre (no relu), hbuf = relu(pre)
__global__ __launch_bounds__(256) void k_atom_fc(const float* __restrict__ atom_list,
                                                 const float* __restrict__ WafcT,
                                                 const float* __restrict__ bias,
                                                 float* __restrict__ out_pre,
                                                 float* __restrict__ hbuf) {
    int bl = blockIdx.x;  // flat atom
    int t = threadIdx.x;
    __shared__ float x[40];
    if (t < AA) x[t] = atom_list[(size_t)bl * AA + t];
    __syncthreads();
    float acc = bias[t];
#pragma unroll
    for (int i = 0; i < AA; ++i) acc += x[i] * WafcT[i * FP + t];
    out_pre[(size_t)bl * FP + t] = acc;
    hbuf[(size_t)bl * FP + t] = fmaxf(acc, 0.f);
}

// ---------------- per-round attention: ctx + aw ----------------
__global__ __launch_bounds__(256) void k_attn(int d,
        const float* __restrict__ actPrev,   // (B*L,FP) relu'd activations
        const float* __restrict__ atom_list,
        const float* __restrict__ bond_list,
        const int* __restrict__ adeg, const int* __restrict__ bdeg,
        const float* __restrict__ WnT, const float* __restrict__ bn,   // neighbor fc (d==0)
        const float* __restrict__ alignW, const float* __restrict__ alignBp,
        const float* __restrict__ WaT, const float* __restrict__ ab,
        float* __restrict__ ctx, float* __restrict__ awv_out) {
    int bl = blockIdx.x;
    int b = bl >> 7, l = bl & (LL - 1);
    (void)l;
    int t = threadIdx.x;
    int wave = t >> 6, lane = t & 63;

    __shared__ float sa[FP];
    __shared__ float nb[KK][FP];
    __shared__ float cbuf[KK][52];
    __shared__ int jidx[KK];
    __shared__ int bidx[KK];
    __shared__ float wred[KK][4];
    __shared__ float scores[KK];
    __shared__ float wn[FP];

    sa[t] = actPrev[(size_t)bl * FP + t];
    if (t < KK) {
        jidx[t] = adeg[bl * KK + t];
        bidx[t] = (d == 0) ? bdeg[bl * KK + t] : 0;
    }
    __syncthreads();

    if (d == 0) {
        // stage concat inputs for all k
        for (int k = 0; k < KK; ++k) {
            int j = jidx[k];
            if (t < AA) cbuf[k][t] = atom_list[((size_t)b * LL + j) * AA + t];
            else if (t < AA + BDD) cbuf[k][t] = bond_list[((size_t)b * MM + bidx[k]) * BDD + (t - AA)];
        }
        __syncthreads();
        for (int k = 0; k < KK; ++k) {
            float acc = bn[t];
#pragma unroll
            for (int i = 0; i < AA + BDD; ++i) acc += cbuf[k][i] * WnT[i * FP + t];
            nb[k][t] = fmaxf(acc, 0.f);
        }
    } else {
        for (int k = 0; k < KK; ++k) {
            int j = jidx[k];
            nb[k][t] = actPrev[((size_t)b * LL + j) * FP + t];
        }
    }
    __syncthreads();

    // scores: dot(concat(self, neigh_k), alignW) + b, relu, pad -> -9
    float w0 = alignW[t], w1 = alignW[FP + t];
    float selfterm = sa[t] * w0;
    for (int k = 0; k < KK; ++k) {
        float v = selfterm + nb[k][t] * w1;
#pragma unroll
        for (int off = 32; off >= 1; off >>= 1) v += __shfl_xor(v, off);
        if (lane == 0) wred[k][wave] = v;
    }
    __syncthreads();
    if (t < KK) {
        float s = wred[t][0] + wred[t][1] + wred[t][2] + wred[t][3] + alignBp[0];
        s = fmaxf(s, 0.f);
        if (jidx[t] == LL - 1) s += -9.0f;
        scores[t] = s;
    }
    __syncthreads();

    // softmax over K (redundant per thread), mask pads
    float m = scores[0];
#pragma unroll
    for (int k = 1; k < KK; ++k) m = fmaxf(m, scores[k]);
    float e[KK], den = 0.f;
#pragma unroll
    for (int k = 0; k < KK; ++k) { e[k] = expf(scores[k] - m); den += e[k]; }
    float aw[KK], sumaw = 0.f;
#pragma unroll
    for (int k = 0; k < KK; ++k) {
        aw[k] = (jidx[k] == LL - 1) ? 0.f : e[k] / den;
        sumaw += aw[k];
    }
    if (t < KK) awv_out[(size_t)bl * KK + t] = aw[t];

    // weighted neighbor sum, then single matvec through attend_W
    float w = 0.f;
#pragma unroll
    for (int k = 0; k < KK; ++k) w += aw[k] * nb[k][t];
    wn[t] = w;
    __syncthreads();

    float acc = 0.f;
    for (int i = 0; i < FP; ++i) acc += wn[i] * WaT[i * FP + t];
    acc += sumaw * ab[t];
    ctx[(size_t)bl * FP + t] = fmaxf(acc, 0.f);
}

// ---------------- GRU over 8 atoms per block ----------------
__global__ __launch_bounds__(256) void k_gru(const float* __restrict__ ctx,
                                             float* __restrict__ hbuf,
                                             const float* __restrict__ WihT,
                                             const float* __restrict__ WhhT,
                                             const float* __restrict__ bih,
                                             const float* __restrict__ bhh,
                                             float* __restrict__ act_out) {
    int g0 = blockIdx.x * 8;
    int t = threadIdx.x;
    __shared__ float cx[8][FP];
    __shared__ float hh[8][FP];
    for (int a = 0; a < 8; ++a) {
        cx[a][t] = ctx[(size_t)(g0 + a) * FP + t];
        hh[a][t] = hbuf[(size_t)(g0 + a) * FP + t];
    }
    __syncthreads();
    float air[8], aiz[8], ain[8], ahr[8], ahz[8], ahn[8];
    float bir = bih[t], biz = bih[FP + t], bin_ = bih[2 * FP + t];
    float bhr = bhh[t], bhz = bhh[FP + t], bhn = bhh[2 * FP + t];
#pragma unroll
    for (int a = 0; a < 8; ++a) {
        air[a] = bir; aiz[a] = biz; ain[a] = bin_;
        ahr[a] = bhr; ahz[a] = bhz; ahn[a] = bhn;
    }
    for (int i = 0; i < FP; ++i) {
        const float* wi = WihT + (size_t)i * 768;
        const float* wh = WhhT + (size_t)i * 768;
        float wir = wi[t], wiz = wi[FP + t], win = wi[2 * FP + t];
        float whr = wh[t], whz = wh[FP + t], whn = wh[2 * FP + t];
#pragma unroll
        for (int a = 0; a < 8; ++a) {
            float c = cx[a][i], h = hh[a][i];
            air[a] += c * wir; aiz[a] += c * wiz; ain[a] += c * win;
            ahr[a] += h * whr; ahz[a] += h * whz; ahn[a] += h * whn;
        }
    }
#pragma unroll
    for (int a = 0; a < 8; ++a) {
        float r = 1.f / (1.f + expf(-(air[a] + ahr[a])));
        float z = 1.f / (1.f + expf(-(aiz[a] + ahz[a])));
        float n = tanhf(ain[a] + r * ahn[a]);
        float hn = (1.f - z) * n + z * hh[a][t];
        hbuf[(size_t)(g0 + a) * FP + t] = hn;
        act_out[(size_t)(g0 + a) * FP + t] = fmaxf(hn, 0.f);
    }
}

// ---------------- mol reductions: mol_unb[0], mfv[0], molF ----------------
__global__ __launch_bounds__(256) void k_mol_reduce(const float* __restrict__ hbuf,
                                                    const float* __restrict__ act,
                                                    const float* __restrict__ mask,
                                                    float* __restrict__ o_unb0,
                                                    float* __restrict__ o_mfv0,
                                                    float* __restrict__ molF) {
    int b = blockIdx.x, t = threadIdx.x;
    float s1 = 0.f, s2 = 0.f;
    for (int l = 0; l < LL; ++l) {
        float mk = mask[b * LL + l];
        s1 += hbuf[((size_t)b * LL + l) * FP + t] * mk;
        s2 += act[((size_t)b * LL + l) * FP + t] * mk;
    }
    o_unb0[b * FP + t] = s1;
    o_mfv0[b * FP + t] = s2;
    molF[b * FP + t] = s2;
}

// ---------------- AV = act @ mol_attend_W.T + b (8 atoms/block) ----------------
__global__ __launch_bounds__(256) void k_av(const float* __restrict__ act,
                                            const float* __restrict__ MWaT,
                                            const float* __restrict__ mab,
                                            float* __restrict__ AV) {
    int g0 = blockIdx.x * 8;
    int t = threadIdx.x;
    __shared__ float xs[8][FP];
    for (int a = 0; a < 8; ++a) xs[a][t] = act[(size_t)(g0 + a) * FP + t];
    __syncthreads();
    float acc[8];
    float bb = mab[t];
#pragma unroll
    for (int a = 0; a < 8; ++a) acc[a] = bb;
    for (int i = 0; i < FP; ++i) {
        float w = MWaT[i * FP + t];
#pragma unroll
        for (int a = 0; a < 8; ++a) acc[a] += xs[a][i] * w;
    }
    for (int a = 0; a < 8; ++a) AV[(size_t)(g0 + a) * FP + t] = acc[a];
}

// ---------------- mol attention + mol GRU, one block per molecule ----------------
__global__ __launch_bounds__(256) void k_mol_step(int step,
        const float* __restrict__ act,       // afv[R] (B,L,FP)
        const float* __restrict__ AV,
        float* __restrict__ molF,
        const float* __restrict__ mask,
        const float* __restrict__ mAw, const float* __restrict__ mAb,
        const float* __restrict__ MihT, const float* __restrict__ MhhT,
        const float* __restrict__ mbih, const float* __restrict__ mbhh,
        float* __restrict__ o_mfv, float* __restrict__ o_unb,
        float* __restrict__ o_mawv, float* __restrict__ o_molfeat) {
    int b = blockIdx.x, t = threadIdx.x;
    int wave = t >> 6, lane = t & 63;
    __shared__ float am[FP], hh[FP], cx[FP];
    __shared__ float S2[LL], mw[LL];
    __shared__ float red[4];

    float hprev = molF[b * FP + t];
    hh[t] = hprev;
    am[t] = fmaxf(hprev, 0.f);
    __syncthreads();

    // self part of align score
    float v = am[t] * mAw[t];
#pragma unroll
    for (int off = 32; off >= 1; off >>= 1) v += __shfl_xor(v, off);
    if (lane == 0) red[wave] = v;
    __syncthreads();
    float s_self = red[0] + red[1] + red[2] + red[3];

    // per-atom part: wave w handles rows l = w, w+4, ...
    for (int l = wave; l < LL; l += 4) {
        float v2 = 0.f;
#pragma unroll
        for (int q = 0; q < 4; ++q) {
            int i = lane + 64 * q;
            v2 += act[((size_t)b * LL + l) * FP + i] * mAw[FP + i];
        }
#pragma unroll
        for (int off = 32; off >= 1; off >>= 1) v2 += __shfl_xor(v2, off);
        if (lane == 0) S2[l] = v2;
    }
    __syncthreads();

    if (t < LL) {
        float s = fmaxf(s_self + S2[t] + mAb[0], 0.f);
        if (mask[b * LL + t] == 0.f) s += -9e8f;
        S2[t] = s;
    }
    __syncthreads();

    // softmax over L (redundant per thread)
    float m = -1e30f;
    for (int l = 0; l < LL; ++l) m = fmaxf(m, S2[l]);
    float den = 0.f;
    for (int l = 0; l < LL; ++l) den += expf(S2[l] - m);
    if (t < LL) {
        float w = expf(S2[t] - m) / den * mask[b * LL + t];
        mw[t] = w;
        o_mawv[(size_t)step * (BB * LL) + b * LL + t] = w;
    }
    __syncthreads();

    // mctx
    float acc = 0.f;
    for (int l = 0; l < LL; ++l) acc += mw[l] * AV[((size_t)b * LL + l) * FP + t];
    cx[t] = fmaxf(acc, 0.f);
    __syncthreads();

    // mol GRU
    float air = mbih[t], aiz = mbih[FP + t], ain = mbih[2 * FP + t];
    float ahr = mbhh[t], ahz = mbhh[FP + t], ahn = mbhh[2 * FP + t];
    for (int i = 0; i < FP; ++i) {
        float c = cx[i], h = hh[i];
        air += c * MihT[i * 768 + t];
        aiz += c * MihT[i * 768 + FP + t];
        ain += c * MihT[i * 768 + 2 * FP + t];
        ahr += h * MhhT[i * 768 + t];
        ahz += h * MhhT[i * 768 + FP + t];
        ahn += h * MhhT[i * 768 + 2 * FP + t];
    }
    float r = 1.f / (1.f + expf(-(air + ahr)));
    float z = 1.f / (1.f + expf(-(aiz + ahz)));
    float n = tanhf(ain + r * ahn);
    float hn = (1.f - z) * n + z * hprev;

    molF[b * FP + t] = hn;
    o_unb[(size_t)(step + 1) * (BB * FP) + b * FP + t] = hn;
    o_mfv[(size_t)(step + 1) * (BB * FP) + b * FP + t] = fmaxf(hn, 0.f);
    if (step == TT - 1) o_molfeat[b * FP + t] = hn;
}

extern "C" void kernel_launch(void* const* d_in, const int* in_sizes, int n_in,
                              void* d_out, int out_size, void* d_ws, size_t ws_size,
                              hipStream_t stream) {
    const float* atom_list = (const float*)d_in[0];
    const float* bond_list = (const float*)d_in[1];
    const int*   adeg      = (const int*)d_in[2];
    const int*   bdeg      = (const int*)d_in[3];
    const float* amask     = (const float*)d_in[4];
    const float* atom_fc_W = (const float*)d_in[5];
    const float* atom_fc_b = (const float*)d_in[6];
    const float* nfc_W     = (const float*)d_in[7];
    const float* nfc_b     = (const float*)d_in[8];
    const float* gwih      = (const float*)d_in[9];
    const float* gwhh      = (const float*)d_in[10];
    const float* gbih      = (const float*)d_in[11];
    const float* gbhh      = (const float*)d_in[12];
    const float* alW       = (const float*)d_in[13];
    const float* alb       = (const float*)d_in[14];
    const float* atW       = (const float*)d_in[15];
    const float* atb       = (const float*)d_in[16];
    const float* mgwih     = (const float*)d_in[17];
    const float* mgwhh     = (const float*)d_in[18];
    const float* mgbih     = (const float*)d_in[19];
    const float* mgbhh     = (const float*)d_in[20];
    const float* malW      = (const float*)d_in[21];
    const float* malb      = (const float*)d_in[22];
    const float* matW      = (const float*)d_in[23];
    const float* matb      = (const float*)d_in[24];

    const size_t BLF = (size_t)BB * LL * FP;        // 8388608
    float* out = (float*)d_out;
    float* O0 = out;                                 // atom_feature / h
    float* O1 = out + BLF;                           // afv (4,B,L,FP)
    float* O2 = O1 + 4 * BLF;                        // awv (3,B,L,K)
    float* O3 = O2 + (size_t)RR * BB * LL * KK;      // mfv (3,B,FP)
    float* O4 = O3 + (size_t)(TT + 1) * BB * FP;     // mol_unb
    float* O5 = O4 + (size_t)(TT + 1) * BB * FP;     // mawv (2,B,L)
    float* O6 = O5 + (size_t)TT * BB * LL;           // mol_feature

    float* ws = (float*)d_ws;
    float* CTX   = ws;                 // B*L*FP floats (also reused as AV)
    float* MOLF  = CTX + BLF;          // B*FP
    float* WafcT = MOLF + (size_t)BB * FP;
    float* WnT   = WafcT + AA * FP;
    float* WaT   = WnT + (AA + BDD) * FP;
    float* WihT  = WaT + (size_t)RR * FP * FP;
    float* WhhT  = WihT + (size_t)RR * FP * 768;
    float* MWaT  = WhhT + (size_t)RR * FP * 768;
    float* MihT  = MWaT + (size_t)FP * FP;
    float* MhhT  = MihT + (size_t)FP * 768;
    (void)ws_size; (void)in_sizes; (void)n_in; (void)out_size;

    auto tr = [&](const float* src, float* dst, int O, int I) {
        int n = O * I;
        k_transpose<<<(n + 255) / 256, 256, 0, stream>>>(src, dst, O, I);
    };
    tr(atom_fc_W, WafcT, FP, AA);
    tr(nfc_W, WnT, FP, AA + BDD);
    for (int d = 0; d < RR; ++d) {
        tr(atW + (size_t)d * FP * FP, WaT + (size_t)d * FP * FP, FP, FP);
        tr(gwih + (size_t)d * FP * 768, WihT + (size_t)d * FP * 768, 768, FP);
        tr(gwhh + (size_t)d * FP * 768, WhhT + (size_t)d * FP * 768, 768, FP);
    }
    tr(matW, MWaT, FP, FP);
    tr(mgwih, MihT, 768, FP);
    tr(mgwhh, MhhT, 768, FP);

    k_atom_fc<<<BB * LL, 256, 0, stream>>>(atom_list, WafcT, atom_fc_b, O1, O0);

    for (int d = 0; d < RR; ++d) {
        const float* actPrev = (d == 0) ? O0 : (O1 + (size_t)d * BLF);
        k_attn<<<BB * LL, 256, 0, stream>>>(d, actPrev, atom_list, bond_list, adeg, bdeg,
                WnT, nfc_b, alW + (size_t)d * 2 * FP, alb + d,
                WaT + (size_t)d * FP * FP, atb + (size_t)d * FP,
                CTX, O2 + (size_t)d * BB * LL * KK);
        k_gru<<<BB * LL / 8, 256, 0, stream>>>(CTX, O0,
                WihT + (size_t)d * FP * 768, WhhT + (size_t)d * FP * 768,
                gbih + (size_t)d * 768, gbhh + (size_t)d * 768,
                O1 + (size_t)(d + 1) * BLF);
    }

    const float* actFin = O1 + (size_t)RR * BLF;
    k_mol_reduce<<<BB, 256, 0, stream>>>(O0, actFin, amask, O4, O3, MOLF);
    k_av<<<BB * LL / 8, 256, 0, stream>>>(actFin, MWaT, matb, CTX);
    for (int st = 0; st < TT; ++st) {
        k_mol_step<<<BB, 256, 0, stream>>>(st, actFin, CTX, MOLF, amask,
                malW, malb, MihT, MhhT, mgbih, mgbhh,
                O3, O4, O5, O6);
    }
}

// Round 2
// 1865.924 us; speedup vs baseline: 1.5267x; 1.5267x over previous
//
#include <hip/hip_runtime.h>
#include <hip/hip_bf16.h>

// Dims
#define BB 256
#define LL 128
#define AA 39
#define BDD 10
#define KK 6
#define MM 256
#define FP 256
#define RR 3
#define TT 2

using short8 = __attribute__((ext_vector_type(8))) short;
using f32x4  = __attribute__((ext_vector_type(4))) float;

__device__ __forceinline__ short f2bf(float f) {
    union { float f; unsigned u; } v; v.f = f;
    unsigned u = v.u;
    u += 0x7fffu + ((u >> 16) & 1u);   // round-to-nearest-even
    return (short)(u >> 16);
}

// ---------------- transpose: dst[i*O+o] = src[o*I+i] ----------------
__global__ __launch_bounds__(256) void k_transpose(const float* __restrict__ src,
                                                   float* __restrict__ dst, int O, int I) {
    int idx = blockIdx.x * 256 + threadIdx.x;
    if (idx >= O * I) return;
    int o = idx / I, i = idx - o * I;
    dst[i * O + o] = src[idx];
}

// ---------------- pack GRU weights into MFMA fragment-major bf16 ----------------
// out layout: [d][mat][ks(8)][nt(48)][lane(64)][j(8)]
// value = W[d][n][k], n = nt*16 + (lane&15), k = ks*32 + (lane>>4)*8 + j
__global__ __launch_bounds__(256) void k_prep_gruw(const float* __restrict__ gwih,
                                                   const float* __restrict__ gwhh,
                                                   short* __restrict__ out) {
    int idx = blockIdx.x * 256 + threadIdx.x;
    if (idx >= RR * 2 * 8 * 48 * 512) return;
    int j = idx & 7;
    int lane = (idx >> 3) & 63;
    int blk = idx >> 9;               // [d][mat][ks][nt] flat
    int nt = blk % 48;
    int ks = (blk / 48) % 8;
    int mat = (blk / (48 * 8)) % 2;
    int d = blk / (48 * 8 * 2);
    int n = nt * 16 + (lane & 15);
    int k = ks * 32 + (lane >> 4) * 8 + j;
    const float* W = mat ? gwhh : gwih;
    out[idx] = f2bf(W[((size_t)d * 768 + n) * FP + k]);
}

// ---------------- atom fc: pre = atom_list @ W.T + b ----------------
__global__ __launch_bounds__(256) void k_atom_fc(const float* __restrict__ atom_list,
                                                 const float* __restrict__ WafcT,
                                                 const float* __restrict__ bias,
                                                 float* __restrict__ out_pre,
                                                 float* __restrict__ hbuf,
                                                 short* __restrict__ hb16) {
    int bl = blockIdx.x;
    int t = threadIdx.x;
    __shared__ float x[40];
    if (t < AA) x[t] = atom_list[(size_t)bl * AA + t];
    __syncthreads();
    float acc = bias[t];
#pragma unroll
    for (int i = 0; i < AA; ++i) acc += x[i] * WafcT[i * FP + t];
    out_pre[(size_t)bl * FP + t] = acc;
    float rl = fmaxf(acc, 0.f);
    hbuf[(size_t)bl * FP + t] = acc;      // h = atom_feature (pre-relu? no!)
    hb16[(size_t)bl * FP + t] = f2bf(acc);
}
// NOTE: reference: h = atom_feature.reshape(...) where atom_feature = relu(pre).
// So h0 = relu(pre). Fixed below in launch comment -- we store relu in hbuf.

__global__ __launch_bounds__(256) void k_atom_fc_fix(const float* __restrict__ atom_list,
                                                     const float* __restrict__ WafcT,
                                                     const float* __restrict__ bias,
                                                     float* __restrict__ out_pre,
                                                     float* __restrict__ hbuf,
                                                     short* __restrict__ hb16) {
    int bl = blockIdx.x;
    int t = threadIdx.x;
    __shared__ float x[40];
    if (t < AA) x[t] = atom_list[(size_t)bl * AA + t];
    __syncthreads();
    float acc = bias[t];
#pragma unroll
    for (int i = 0; i < AA; ++i) acc += x[i] * WafcT[i * FP + t];
    out_pre[(size_t)bl * FP + t] = acc;
    float rl = fmaxf(acc, 0.f);
    hbuf[(size_t)bl * FP + t] = rl;
    hb16[(size_t)bl * FP + t] = f2bf(rl);
}

// ---------------- per-round attention: ctx (bf16) + aw ----------------
__global__ __launch_bounds__(256) void k_attn(int d,
        const float* __restrict__ actPrev,
        const float* __restrict__ atom_list,
        const float* __restrict__ bond_list,
        const int* __restrict__ adeg, const int* __restrict__ bdeg,
        const float* __restrict__ WnT, const float* __restrict__ bn,
        const float* __restrict__ alignW, const float* __restrict__ alignBp,
        const float* __restrict__ WaT, const float* __restrict__ ab,
        short* __restrict__ ctxb, float* __restrict__ awv_out) {
    int bl = blockIdx.x;
    int b = bl >> 7;
    int t = threadIdx.x;
    int wave = t >> 6, lane = t & 63;

    __shared__ float sa[FP];
    __shared__ float nb[KK][FP];
    __shared__ float cbuf[KK][52];
    __shared__ int jidx[KK];
    __shared__ int bidx[KK];
    __shared__ float wred[KK][4];
    __shared__ float scores[KK];
    __shared__ float wn[FP];

    sa[t] = actPrev[(size_t)bl * FP + t];
    if (t < KK) {
        jidx[t] = adeg[bl * KK + t];
        bidx[t] = (d == 0) ? bdeg[bl * KK + t] : 0;
    }
    __syncthreads();

    if (d == 0) {
        for (int k = 0; k < KK; ++k) {
            int j = jidx[k];
            if (t < AA) cbuf[k][t] = atom_list[((size_t)b * LL + j) * AA + t];
            else if (t < AA + BDD) cbuf[k][t] = bond_list[((size_t)b * MM + bidx[k]) * BDD + (t - AA)];
        }
        __syncthreads();
        for (int k = 0; k < KK; ++k) {
            float acc = bn[t];
#pragma unroll
            for (int i = 0; i < AA + BDD; ++i) acc += cbuf[k][i] * WnT[i * FP + t];
            nb[k][t] = fmaxf(acc, 0.f);
        }
    } else {
        for (int k = 0; k < KK; ++k) {
            int j = jidx[k];
            nb[k][t] = actPrev[((size_t)b * LL + j) * FP + t];
        }
    }
    __syncthreads();

    float w0 = alignW[t], w1 = alignW[FP + t];
    float selfterm = sa[t] * w0;
    for (int k = 0; k < KK; ++k) {
        float v = selfterm + nb[k][t] * w1;
#pragma unroll
        for (int off = 32; off >= 1; off >>= 1) v += __shfl_xor(v, off);
        if (lane == 0) wred[k][wave] = v;
    }
    __syncthreads();
    if (t < KK) {
        float s = wred[t][0] + wred[t][1] + wred[t][2] + wred[t][3] + alignBp[0];
        s = fmaxf(s, 0.f);
        if (jidx[t] == LL - 1) s += -9.0f;
        scores[t] = s;
    }
    __syncthreads();

    float m = scores[0];
#pragma unroll
    for (int k = 1; k < KK; ++k) m = fmaxf(m, scores[k]);
    float e[KK], den = 0.f;
#pragma unroll
    for (int k = 0; k < KK; ++k) { e[k] = expf(scores[k] - m); den += e[k]; }
    float aw[KK], sumaw = 0.f;
#pragma unroll
    for (int k = 0; k < KK; ++k) {
        aw[k] = (jidx[k] == LL - 1) ? 0.f : e[k] / den;
        sumaw += aw[k];
    }
    if (t < KK) awv_out[(size_t)bl * KK + t] = aw[t];

    float w = 0.f;
#pragma unroll
    for (int k = 0; k < KK; ++k) w += aw[k] * nb[k][t];
    wn[t] = w;
    __syncthreads();

    float acc = 0.f;
    for (int i = 0; i < FP; ++i) acc += wn[i] * WaT[i * FP + t];
    acc += sumaw * ab[t];
    ctxb[(size_t)bl * FP + t] = f2bf(fmaxf(acc, 0.f));
}

// ---------------- fused MFMA GRU: 32 atoms/block, 8 waves ----------------
// GI = ctx @ Wih^T, GH = h @ Whh^T via mfma_f32_16x16x32_bf16, lane-local gates.
__global__ __launch_bounds__(512) void k_gru_mfma(
        const short* __restrict__ XB,     // ctx bf16 (B*L, FP)
        const short* __restrict__ HBl,    // h bf16 (read)
        float* __restrict__ hbuf,         // h fp32 (read old, write new)
        const short* __restrict__ Bih,    // frag-major (8,48,64,8)
        const short* __restrict__ Bhh,
        const float* __restrict__ bih, const float* __restrict__ bhh,
        float* __restrict__ act_out,      // afv slot (relu h)
        short* __restrict__ HB_out) {
    int t = threadIdx.x;
    int wave = t >> 6, lane = t & 63;
    int abase = blockIdx.x * 32 + (wave >> 2) * 16;
    int wn = wave & 3;
    int lr = lane & 15, lk = lane >> 4;

    f32x4 acc_i[3][4] = {};
    f32x4 acc_h[3][4] = {};

    const short8* xrow = (const short8*)(XB + (size_t)(abase + lr) * FP);
    const short8* hrow = (const short8*)(HBl + (size_t)(abase + lr) * FP);
    const short8* bi8 = (const short8*)Bih;
    const short8* bh8 = (const short8*)Bhh;

    for (int ks = 0; ks < 8; ++ks) {
        short8 ax = xrow[ks * 4 + lk];
        short8 ah = hrow[ks * 4 + lk];
#pragma unroll
        for (int g = 0; g < 3; ++g) {
#pragma unroll
            for (int sub = 0; sub < 4; ++sub) {
                int nt = g * 16 + wn * 4 + sub;
                size_t o = (size_t)(ks * 48 + nt) * 64 + lane;
                acc_i[g][sub] = __builtin_amdgcn_mfma_f32_16x16x32_bf16(ax, bi8[o], acc_i[g][sub], 0, 0, 0);
                acc_h[g][sub] = __builtin_amdgcn_mfma_f32_16x16x32_bf16(ah, bh8[o], acc_h[g][sub], 0, 0, 0);
            }
        }
    }
    __syncthreads();   // all HBl reads complete before HB_out writes

#pragma unroll
    for (int sub = 0; sub < 4; ++sub) {
        int c = wn * 64 + sub * 16 + lr;
        float bir = bih[c], biz = bih[FP + c], bin_ = bih[2 * FP + c];
        float bhr = bhh[c], bhz = bhh[FP + c], bhn = bhh[2 * FP + c];
#pragma unroll
        for (int q = 0; q < 4; ++q) {
            int atom = abase + lk * 4 + q;
            size_t idx = (size_t)atom * FP + c;
            float hold = hbuf[idx];
            float r = 1.f / (1.f + expf(-(acc_i[0][sub][q] + bir + acc_h[0][sub][q] + bhr)));
            float z = 1.f / (1.f + expf(-(acc_i[1][sub][q] + biz + acc_h[1][sub][q] + bhz)));
            float n = tanhf(acc_i[2][sub][q] + bin_ + r * (acc_h[2][sub][q] + bhn));
            float hn = (1.f - z) * n + z * hold;
            hbuf[idx] = hn;
            act_out[idx] = fmaxf(hn, 0.f);
            HB_out[idx] = f2bf(hn);
        }
    }
}

// ---------------- mol reductions ----------------
__global__ __launch_bounds__(256) void k_mol_reduce(const float* __restrict__ hbuf,
                                                    const float* __restrict__ act,
                                                    const float* __restrict__ mask,
                                                    float* __restrict__ o_unb0,
                                                    float* __restrict__ o_mfv0,
                                                    float* __restrict__ molF) {
    int b = blockIdx.x, t = threadIdx.x;
    float s1 = 0.f, s2 = 0.f;
    for (int l = 0; l < LL; ++l) {
        float mk = mask[b * LL + l];
        s1 += hbuf[((size_t)b * LL + l) * FP + t] * mk;
        s2 += act[((size_t)b * LL + l) * FP + t] * mk;
    }
    o_unb0[b * FP + t] = s1;
    o_mfv0[b * FP + t] = s2;
    molF[b * FP + t] = s2;
}

// ---------------- AV = act @ mol_attend_W.T + b ----------------
__global__ __launch_bounds__(256) void k_av(const float* __restrict__ act,
                                            const float* __restrict__ MWaT,
                                            const float* __restrict__ mab,
                                            float* __restrict__ AV) {
    int g0 = blockIdx.x * 8;
    int t = threadIdx.x;
    __shared__ float xs[8][FP];
    for (int a = 0; a < 8; ++a) xs[a][t] = act[(size_t)(g0 + a) * FP + t];
    __syncthreads();
    float acc[8];
    float bb2 = mab[t];
#pragma unroll
    for (int a = 0; a < 8; ++a) acc[a] = bb2;
    for (int i = 0; i < FP; ++i) {
        float w = MWaT[i * FP + t];
#pragma unroll
        for (int a = 0; a < 8; ++a) acc[a] += xs[a][i] * w;
    }
    for (int a = 0; a < 8; ++a) AV[(size_t)(g0 + a) * FP + t] = acc[a];
}

// ---------------- mol attention + mol GRU ----------------
__global__ __launch_bounds__(256) void k_mol_step(int step,
        const float* __restrict__ act,
        const float* __restrict__ AV,
        float* __restrict__ molF,
        const float* __restrict__ mask,
        const float* __restrict__ mAw, const float* __restrict__ mAb,
        const float* __restrict__ MihT, const float* __restrict__ MhhT,
        const float* __restrict__ mbih, const float* __restrict__ mbhh,
        float* __restrict__ o_mfv, float* __restrict__ o_unb,
        float* __restrict__ o_mawv, float* __restrict__ o_molfeat) {
    int b = blockIdx.x, t = threadIdx.x;
    int wave = t >> 6, lane = t & 63;
    __shared__ float am[FP], hh[FP], cx[FP];
    __shared__ float S2[LL], mw[LL];
    __shared__ float red[4];

    float hprev = molF[b * FP + t];
    hh[t] = hprev;
    am[t] = fmaxf(hprev, 0.f);
    __syncthreads();

    float v = am[t] * mAw[t];
#pragma unroll
    for (int off = 32; off >= 1; off >>= 1) v += __shfl_xor(v, off);
    if (lane == 0) red[wave] = v;
    __syncthreads();
    float s_self = red[0] + red[1] + red[2] + red[3];

    for (int l = wave; l < LL; l += 4) {
        float v2 = 0.f;
#pragma unroll
        for (int q = 0; q < 4; ++q) {
            int i = lane + 64 * q;
            v2 += act[((size_t)b * LL + l) * FP + i] * mAw[FP + i];
        }
#pragma unroll
        for (int off = 32; off >= 1; off >>= 1) v2 += __shfl_xor(v2, off);
        if (lane == 0) S2[l] = v2;
    }
    __syncthreads();

    if (t < LL) {
        float s = fmaxf(s_self + S2[t] + mAb[0], 0.f);
        if (mask[b * LL + t] == 0.f) s += -9e8f;
        S2[t] = s;
    }
    __syncthreads();

    float m = -1e30f;
    for (int l = 0; l < LL; ++l) m = fmaxf(m, S2[l]);
    float den = 0.f;
    for (int l = 0; l < LL; ++l) den += expf(S2[l] - m);
    if (t < LL) {
        float w = expf(S2[t] - m) / den * mask[b * LL + t];
        mw[t] = w;
        o_mawv[(size_t)step * (BB * LL) + b * LL + t] = w;
    }
    __syncthreads();

    float acc = 0.f;
    for (int l = 0; l < LL; ++l) acc += mw[l] * AV[((size_t)b * LL + l) * FP + t];
    cx[t] = fmaxf(acc, 0.f);
    __syncthreads();

    float air = mbih[t], aiz = mbih[FP + t], ain = mbih[2 * FP + t];
    float ahr = mbhh[t], ahz = mbhh[FP + t], ahn = mbhh[2 * FP + t];
    for (int i = 0; i < FP; ++i) {
        float c = cx[i], h = hh[i];
        air += c * MihT[i * 768 + t];
        aiz += c * MihT[i * 768 + FP + t];
        ain += c * MihT[i * 768 + 2 * FP + t];
        ahr += h * MhhT[i * 768 + t];
        ahz += h * MhhT[i * 768 + FP + t];
        ahn += h * MhhT[i * 768 + 2 * FP + t];
    }
    float r = 1.f / (1.f + expf(-(air + ahr)));
    float z = 1.f / (1.f + expf(-(aiz + ahz)));
    float n = tanhf(ain + r * ahn);
    float hn = (1.f - z) * n + z * hprev;

    molF[b * FP + t] = hn;
    o_unb[(size_t)(step + 1) * (BB * FP) + b * FP + t] = hn;
    o_mfv[(size_t)(step + 1) * (BB * FP) + b * FP + t] = fmaxf(hn, 0.f);
    if (step == TT - 1) o_molfeat[b * FP + t] = hn;
}

extern "C" void kernel_launch(void* const* d_in, const int* in_sizes, int n_in,
                              void* d_out, int out_size, void* d_ws, size_t ws_size,
                              hipStream_t stream) {
    const float* atom_list = (const float*)d_in[0];
    const float* bond_list = (const float*)d_in[1];
    const int*   adeg      = (const int*)d_in[2];
    const int*   bdeg      = (const int*)d_in[3];
    const float* amask     = (const float*)d_in[4];
    const float* atom_fc_W = (const float*)d_in[5];
    const float* atom_fc_b = (const float*)d_in[6];
    const float* nfc_W     = (const float*)d_in[7];
    const float* nfc_b     = (const float*)d_in[8];
    const float* gwih      = (const float*)d_in[9];
    const float* gwhh      = (const float*)d_in[10];
    const float* gbih      = (const float*)d_in[11];
    const float* gbhh      = (const float*)d_in[12];
    const float* alW       = (const float*)d_in[13];
    const float* alb       = (const float*)d_in[14];
    const float* atW       = (const float*)d_in[15];
    const float* atb       = (const float*)d_in[16];
    const float* mgwih     = (const float*)d_in[17];
    const float* mgwhh     = (const float*)d_in[18];
    const float* mgbih     = (const float*)d_in[19];
    const float* mgbhh     = (const float*)d_in[20];
    const float* malW      = (const float*)d_in[21];
    const float* malb      = (const float*)d_in[22];
    const float* matW      = (const float*)d_in[23];
    const float* matb      = (const float*)d_in[24];

    const size_t BLF = (size_t)BB * LL * FP;
    float* out = (float*)d_out;
    float* O0 = out;                                 // atom_feature / h
    float* O1 = out + BLF;                           // afv (4,B,L,FP)
    float* O2 = O1 + 4 * BLF;                        // awv (3,B,L,K)
    float* O3 = O2 + (size_t)RR * BB * LL * KK;      // mfv
    float* O4 = O3 + (size_t)(TT + 1) * BB * FP;     // mol_unb
    float* O5 = O4 + (size_t)(TT + 1) * BB * FP;     // mawv
    float* O6 = O5 + (size_t)TT * BB * LL;           // mol_feature

    // ws layout: [XB bf16 | HB bf16] (= exactly B*L*FP floats, aliased by AV later)
    float* ws = (float*)d_ws;
    short* XB  = (short*)ws;                         // B*L*FP bf16
    short* HBb = XB + BLF;                           // B*L*FP bf16
    float* AV  = ws;                                 // aliases XB+HBb (mol phase only)
    float* MOLF  = (float*)(XB + 2 * BLF);
    float* WafcT = MOLF + (size_t)BB * FP;
    float* WnT   = WafcT + AA * FP;
    float* WaT   = WnT + (AA + BDD) * FP;
    float* MWaT  = WaT + (size_t)RR * FP * FP;
    float* MihT  = MWaT + (size_t)FP * FP;
    float* MhhT  = MihT + (size_t)FP * 768;
    short* GW    = (short*)(MhhT + (size_t)FP * 768);  // RR*2*8*48*512 bf16
    (void)ws_size; (void)in_sizes; (void)n_in; (void)out_size;

    auto tr = [&](const float* src, float* dst, int O, int I) {
        int n = O * I;
        k_transpose<<<(n + 255) / 256, 256, 0, stream>>>(src, dst, O, I);
    };
    tr(atom_fc_W, WafcT, FP, AA);
    tr(nfc_W, WnT, FP, AA + BDD);
    for (int d = 0; d < RR; ++d)
        tr(atW + (size_t)d * FP * FP, WaT + (size_t)d * FP * FP, FP, FP);
    tr(matW, MWaT, FP, FP);
    tr(mgwih, MihT, 768, FP);
    tr(mgwhh, MhhT, 768, FP);
    {
        int n = RR * 2 * 8 * 48 * 512;
        k_prep_gruw<<<(n + 255) / 256, 256, 0, stream>>>(gwih, gwhh, GW);
    }

    k_atom_fc_fix<<<BB * LL, 256, 0, stream>>>(atom_list, WafcT, atom_fc_b, O1, O0, HBb);

    for (int d = 0; d < RR; ++d) {
        const float* actPrev = (d == 0) ? O0 : (O1 + (size_t)d * BLF);
        k_attn<<<BB * LL, 256, 0, stream>>>(d, actPrev, atom_list, bond_list, adeg, bdeg,
                WnT, nfc_b, alW + (size_t)d * 2 * FP, alb + d,
                WaT + (size_t)d * FP * FP, atb + (size_t)d * FP,
                XB, O2 + (size_t)d * BB * LL * KK);
        const size_t wblk = (size_t)8 * 48 * 512;
        k_gru_mfma<<<BB * LL / 32, 512, 0, stream>>>(XB, HBb, O0,
                GW + (size_t)(d * 2 + 0) * wblk, GW + (size_t)(d * 2 + 1) * wblk,
                gbih + (size_t)d * 768, gbhh + (size_t)d * 768,
                O1 + (size_t)(d + 1) * BLF, HBb);
    }

    const float* actFin = O1 + (size_t)RR * BLF;
    k_mol_reduce<<<BB, 256, 0, stream>>>(O0, actFin, amask, O4, O3, MOLF);
    k_av<<<BB * LL / 8, 256, 0, stream>>>(actFin, MWaT, matb, AV);
    for (int st = 0; st < TT; ++st) {
        k_mol_step<<<BB, 256, 0, stream>>>(st, actFin, AV, MOLF, amask,
                malW, malb, MihT, MhhT, mgbih, mgbhh,
                O3, O4, O5, O6);
    }
}

// Round 3
// 1171.000 us; speedup vs baseline: 2.4327x; 1.5934x over previous
//
#include <hip/hip_runtime.h>
#include <hip/hip_bf16.h>

// Dims
#define BB 256
#define LL 128
#define AA 39
#define BDD 10
#define KK 6
#define MM 256
#define FP 256
#define RR 3
#define TT 2

using short8 = __attribute__((ext_vector_type(8))) short;
using f32x4  = __attribute__((ext_vector_type(4))) float;

__device__ __forceinline__ short f2bf(float f) {
    union { float f; unsigned u; } v; v.f = f;
    unsigned u = v.u;
    u += 0x7fffu + ((u >> 16) & 1u);   // round-to-nearest-even
    return (short)(u >> 16);
}

// ---------------- transpose: dst[i*O+o] = src[o*I+i] ----------------
__global__ __launch_bounds__(256) void k_transpose(const float* __restrict__ src,
                                                   float* __restrict__ dst, int O, int I) {
    int idx = blockIdx.x * 256 + threadIdx.x;
    if (idx >= O * I) return;
    int o = idx / I, i = idx - o * I;
    dst[i * O + o] = src[idx];
}

// ---------------- pack a (n x 256) weight matrix into MFMA fragment-major bf16 ----
// out layout: [ks(8)][nt(NT)][lane(64)][j(8)]; n = nt*16+(lane&15), k = ks*32+(lane>>4)*8+j
__global__ __launch_bounds__(256) void k_prep_frag(const float* __restrict__ W,
                                                   short* __restrict__ out, int NT) {
    int idx = blockIdx.x * 256 + threadIdx.x;
    if (idx >= NT * 8 * 512) return;
    int j = idx & 7;
    int lane = (idx >> 3) & 63;
    int blk = idx >> 9;
    int nt = blk % NT;
    int ks = blk / NT;
    int n = nt * 16 + (lane & 15);
    int k = ks * 32 + (lane >> 4) * 8 + j;
    out[idx] = f2bf(W[(size_t)n * FP + k]);
}

// ---------------- atom fc (8 atoms/block): pre -> O1[0], relu -> h, bf16 h ------
__global__ __launch_bounds__(256) void k_atom_fc8(const float* __restrict__ atom_list,
                                                  const float* __restrict__ WafcT,
                                                  const float* __restrict__ bias,
                                                  float* __restrict__ out_pre,
                                                  float* __restrict__ hbuf,
                                                  short* __restrict__ hb16) {
    int g0 = blockIdx.x * 8;
    int t = threadIdx.x;
    __shared__ float x[8][AA];
    for (int i = t; i < 8 * AA; i += 256) x[i / AA][i % AA] = atom_list[(size_t)g0 * AA + i];
    __syncthreads();
    float acc[8];
    float bv = bias[t];
#pragma unroll
    for (int a = 0; a < 8; ++a) acc[a] = bv;
    for (int i = 0; i < AA; ++i) {
        float w = WafcT[i * FP + t];
#pragma unroll
        for (int a = 0; a < 8; ++a) acc[a] += x[a][i] * w;
    }
#pragma unroll
    for (int a = 0; a < 8; ++a) {
        size_t idx = (size_t)(g0 + a) * FP + t;
        out_pre[idx] = acc[a];
        float rl = fmaxf(acc[a], 0.f);
        hbuf[idx] = rl;
        hb16[idx] = f2bf(rl);
    }
}

// ---------------- A_pre = atom_list @ WnA^T + bn (atom part of neighbor fc) ----
__global__ __launch_bounds__(256) void k_apre(const float* __restrict__ atom_list,
                                              const float* __restrict__ WnT,
                                              const float* __restrict__ bn,
                                              float* __restrict__ Apre) {
    int g0 = blockIdx.x * 8;
    int t = threadIdx.x;
    __shared__ float x[8][AA];
    for (int i = t; i < 8 * AA; i += 256) x[i / AA][i % AA] = atom_list[(size_t)g0 * AA + i];
    __syncthreads();
    float acc[8];
    float bv = bn[t];
#pragma unroll
    for (int a = 0; a < 8; ++a) acc[a] = bv;
    for (int i = 0; i < AA; ++i) {
        float w = WnT[i * FP + t];
#pragma unroll
        for (int a = 0; a < 8; ++a) acc[a] += x[a][i] * w;
    }
#pragma unroll
    for (int a = 0; a < 8; ++a) Apre[(size_t)(g0 + a) * FP + t] = acc[a];
}

// ---------------- attention scores + weighted neighbor sum: one wave per atom ----
// Outputs: aw (O2), wn bf16 (XB), sumaw (SW)
__global__ __launch_bounds__(256) void k_awn(int d,
        const float* __restrict__ actPrev,
        const float* __restrict__ bond_list,
        const float* __restrict__ Apre,
        const int* __restrict__ adeg, const int* __restrict__ bdeg,
        const float* __restrict__ WnT,
        const float* __restrict__ alignW, const float* __restrict__ alignBp,
        short* __restrict__ wn_out, float* __restrict__ sw_out,
        float* __restrict__ awv_out) {
    int wv = threadIdx.x >> 6, lane = threadIdx.x & 63;
    int a = blockIdx.x * 4 + wv;
    int b = a >> 7;

    float w0[4], w1[4];
#pragma unroll
    for (int q = 0; q < 4; ++q) { int c = lane + 64 * q; w0[q] = alignW[c]; w1[q] = alignW[FP + c]; }

    // self score
    float ss = 0.f;
#pragma unroll
    for (int q = 0; q < 4; ++q) ss += actPrev[(size_t)a * FP + lane + 64 * q] * w0[q];
#pragma unroll
    for (int off = 32; off; off >>= 1) ss += __shfl_xor(ss, off);
    float bias = alignBp[0];

    float nf[KK][4];
    float sc[KK];
    int jx[KK];
    for (int k = 0; k < KK; ++k) {
        int j = adeg[a * KK + k];
        jx[k] = j;
        size_t rb = ((size_t)(b * LL + j)) * FP;
        if (d == 0) {
            int bi = bdeg[a * KK + k];
            const float* blp = bond_list + ((size_t)b * MM + bi) * BDD;
            float bb[BDD];
#pragma unroll
            for (int i = 0; i < BDD; ++i) bb[i] = blp[i];
#pragma unroll
            for (int q = 0; q < 4; ++q) {
                int c = lane + 64 * q;
                float v = Apre[rb + c];
#pragma unroll
                for (int i = 0; i < BDD; ++i) v += bb[i] * WnT[(AA + i) * FP + c];
                nf[k][q] = fmaxf(v, 0.f);
            }
        } else {
#pragma unroll
            for (int q = 0; q < 4; ++q) nf[k][q] = actPrev[rb + lane + 64 * q];
        }
        float s2 = 0.f;
#pragma unroll
        for (int q = 0; q < 4; ++q) s2 += nf[k][q] * w1[q];
#pragma unroll
        for (int off = 32; off; off >>= 1) s2 += __shfl_xor(s2, off);
        float s = fmaxf(ss + s2 + bias, 0.f);
        if (j == LL - 1) s -= 9.0f;
        sc[k] = s;
    }

    // softmax over K (redundant across lanes — all lanes hold identical sc[])
    float m = sc[0];
#pragma unroll
    for (int k = 1; k < KK; ++k) m = fmaxf(m, sc[k]);
    float e[KK], den = 0.f;
#pragma unroll
    for (int k = 0; k < KK; ++k) { e[k] = expf(sc[k] - m); den += e[k]; }
    float aw[KK], sumaw = 0.f;
#pragma unroll
    for (int k = 0; k < KK; ++k) {
        aw[k] = (jx[k] == LL - 1) ? 0.f : e[k] / den;
        sumaw += aw[k];
    }
    if (lane < KK) {
        float v = aw[0];
#pragma unroll
        for (int k = 1; k < KK; ++k) if (lane == k) v = aw[k];
        awv_out[(size_t)a * KK + lane] = v;
    }
    if (lane == 0) sw_out[a] = sumaw;

#pragma unroll
    for (int q = 0; q < 4; ++q) {
        float w = 0.f;
#pragma unroll
        for (int k = 0; k < KK; ++k) w += aw[k] * nf[k][q];
        wn_out[(size_t)a * FP + lane + 64 * q] = f2bf(w);
    }
}

// ---------------- ctx = relu(WN @ Wa^T + sumaw*ab) via MFMA (32 atoms/block) ----
__global__ __launch_bounds__(512) void k_ctx_mfma(
        const short* __restrict__ XB,      // wn bf16
        const float* __restrict__ SW,
        const short* __restrict__ WaF,     // frag-major (8,16,64,8)
        const float* __restrict__ ab,
        short* __restrict__ ctx_out) {
    int t = threadIdx.x;
    int wave = t >> 6, lane = t & 63;
    int abase = blockIdx.x * 32 + (wave >> 2) * 16;
    int wn4 = wave & 3;
    int lr = lane & 15, lk = lane >> 4;

    f32x4 acc[4] = {};
    const short8* xrow = (const short8*)(XB + (size_t)(abase + lr) * FP);
    const short8* bw = (const short8*)WaF;

    for (int ks = 0; ks < 8; ++ks) {
        short8 ax = xrow[ks * 4 + lk];
#pragma unroll
        for (int sub = 0; sub < 4; ++sub) {
            int nt = wn4 * 4 + sub;
            acc[sub] = __builtin_amdgcn_mfma_f32_16x16x32_bf16(ax, bw[(size_t)(ks * 16 + nt) * 64 + lane], acc[sub], 0, 0, 0);
        }
    }
#pragma unroll
    for (int sub = 0; sub < 4; ++sub) {
        int c = wn4 * 64 + sub * 16 + lr;
        float abc = ab[c];
#pragma unroll
        for (int q = 0; q < 4; ++q) {
            int atom = abase + lk * 4 + q;
            float v = acc[sub][q] + SW[atom] * abc;
            ctx_out[(size_t)atom * FP + c] = f2bf(fmaxf(v, 0.f));
        }
    }
}

// ---------------- fused MFMA GRU: 32 atoms/block, 8 waves ----------------
__global__ __launch_bounds__(512) void k_gru_mfma(
        const short* __restrict__ XB,     // ctx bf16
        const short* __restrict__ HBl,    // h bf16 (read)
        float* __restrict__ hbuf,         // h fp32 (read old, write new)
        const short* __restrict__ Bih,    // frag-major (8,48,64,8)
        const short* __restrict__ Bhh,
        const float* __restrict__ bih, const float* __restrict__ bhh,
        float* __restrict__ act_out,
        short* __restrict__ HB_out) {
    int t = threadIdx.x;
    int wave = t >> 6, lane = t & 63;
    int abase = blockIdx.x * 32 + (wave >> 2) * 16;
    int wn = wave & 3;
    int lr = lane & 15, lk = lane >> 4;

    f32x4 acc_i[3][4] = {};
    f32x4 acc_h[3][4] = {};

    const short8* xrow = (const short8*)(XB + (size_t)(abase + lr) * FP);
    const short8* hrow = (const short8*)(HBl + (size_t)(abase + lr) * FP);
    const short8* bi8 = (const short8*)Bih;
    const short8* bh8 = (const short8*)Bhh;

    for (int ks = 0; ks < 8; ++ks) {
        short8 ax = xrow[ks * 4 + lk];
        short8 ah = hrow[ks * 4 + lk];
#pragma unroll
        for (int g = 0; g < 3; ++g) {
#pragma unroll
            for (int sub = 0; sub < 4; ++sub) {
                int nt = g * 16 + wn * 4 + sub;
                size_t o = (size_t)(ks * 48 + nt) * 64 + lane;
                acc_i[g][sub] = __builtin_amdgcn_mfma_f32_16x16x32_bf16(ax, bi8[o], acc_i[g][sub], 0, 0, 0);
                acc_h[g][sub] = __builtin_amdgcn_mfma_f32_16x16x32_bf16(ah, bh8[o], acc_h[g][sub], 0, 0, 0);
            }
        }
    }
    __syncthreads();   // all HBl reads complete before HB_out writes

#pragma unroll
    for (int sub = 0; sub < 4; ++sub) {
        int c = wn * 64 + sub * 16 + lr;
        float bir = bih[c], biz = bih[FP + c], bin_ = bih[2 * FP + c];
        float bhr = bhh[c], bhz = bhh[FP + c], bhn = bhh[2 * FP + c];
#pragma unroll
        for (int q = 0; q < 4; ++q) {
            int atom = abase + lk * 4 + q;
            size_t idx = (size_t)atom * FP + c;
            float hold = hbuf[idx];
            float r = 1.f / (1.f + expf(-(acc_i[0][sub][q] + bir + acc_h[0][sub][q] + bhr)));
            float z = 1.f / (1.f + expf(-(acc_i[1][sub][q] + biz + acc_h[1][sub][q] + bhz)));
            float n = tanhf(acc_i[2][sub][q] + bin_ + r * (acc_h[2][sub][q] + bhn));
            float hn = (1.f - z) * n + z * hold;
            hbuf[idx] = hn;
            act_out[idx] = fmaxf(hn, 0.f);
            HB_out[idx] = f2bf(hn);
        }
    }
}

// ---------------- mol reductions ----------------
__global__ __launch_bounds__(256) void k_mol_reduce(const float* __restrict__ hbuf,
                                                    const float* __restrict__ act,
                                                    const float* __restrict__ mask,
                                                    float* __restrict__ o_unb0,
                                                    float* __restrict__ o_mfv0,
                                                    float* __restrict__ molF) {
    int b = blockIdx.x, t = threadIdx.x;
    float s1 = 0.f, s2 = 0.f;
    for (int l = 0; l < LL; ++l) {
        float mk = mask[b * LL + l];
        s1 += hbuf[((size_t)b * LL + l) * FP + t] * mk;
        s2 += act[((size_t)b * LL + l) * FP + t] * mk;
    }
    o_unb0[b * FP + t] = s1;
    o_mfv0[b * FP + t] = s2;
    molF[b * FP + t] = s2;
}

// ---------------- AV = act @ mol_attend_W.T + b ----------------
__global__ __launch_bounds__(256) void k_av(const float* __restrict__ act,
                                            const float* __restrict__ MWaT,
                                            const float* __restrict__ mab,
                                            float* __restrict__ AV) {
    int g0 = blockIdx.x * 8;
    int t = threadIdx.x;
    __shared__ float xs[8][FP];
    for (int a = 0; a < 8; ++a) xs[a][t] = act[(size_t)(g0 + a) * FP + t];
    __syncthreads();
    float acc[8];
    float bb2 = mab[t];
#pragma unroll
    for (int a = 0; a < 8; ++a) acc[a] = bb2;
    for (int i = 0; i < FP; ++i) {
        float w = MWaT[i * FP + t];
#pragma unroll
        for (int a = 0; a < 8; ++a) acc[a] += xs[a][i] * w;
    }
    for (int a = 0; a < 8; ++a) AV[(size_t)(g0 + a) * FP + t] = acc[a];
}

// ---------------- mol attention + mol GRU ----------------
__global__ __launch_bounds__(256) void k_mol_step(int step,
        const float* __restrict__ act,
        const float* __restrict__ AV,
        float* __restrict__ molF,
        const float* __restrict__ mask,
        const float* __restrict__ mAw, const float* __restrict__ mAb,
        const float* __restrict__ MihT, const float* __restrict__ MhhT,
        const float* __restrict__ mbih, const float* __restrict__ mbhh,
        float* __restrict__ o_mfv, float* __restrict__ o_unb,
        float* __restrict__ o_mawv, float* __restrict__ o_molfeat) {
    int b = blockIdx.x, t = threadIdx.x;
    int wave = t >> 6, lane = t & 63;
    __shared__ float am[FP], hh[FP], cx[FP];
    __shared__ float S2[LL], mw[LL];
    __shared__ float red[4];

    float hprev = molF[b * FP + t];
    hh[t] = hprev;
    am[t] = fmaxf(hprev, 0.f);
    __syncthreads();

    float v = am[t] * mAw[t];
#pragma unroll
    for (int off = 32; off >= 1; off >>= 1) v += __shfl_xor(v, off);
    if (lane == 0) red[wave] = v;
    __syncthreads();
    float s_self = red[0] + red[1] + red[2] + red[3];

    for (int l = wave; l < LL; l += 4) {
        float v2 = 0.f;
#pragma unroll
        for (int q = 0; q < 4; ++q) {
            int i = lane + 64 * q;
            v2 += act[((size_t)b * LL + l) * FP + i] * mAw[FP + i];
        }
#pragma unroll
        for (int off = 32; off >= 1; off >>= 1) v2 += __shfl_xor(v2, off);
        if (lane == 0) S2[l] = v2;
    }
    __syncthreads();

    if (t < LL) {
        float s = fmaxf(s_self + S2[t] + mAb[0], 0.f);
        if (mask[b * LL + t] == 0.f) s += -9e8f;
        S2[t] = s;
    }
    __syncthreads();

    float m = -1e30f;
    for (int l = 0; l < LL; ++l) m = fmaxf(m, S2[l]);
    float den = 0.f;
    for (int l = 0; l < LL; ++l) den += expf(S2[l] - m);
    if (t < LL) {
        float w = expf(S2[t] - m) / den * mask[b * LL + t];
        mw[t] = w;
        o_mawv[(size_t)step * (BB * LL) + b * LL + t] = w;
    }
    __syncthreads();

    float acc = 0.f;
    for (int l = 0; l < LL; ++l) acc += mw[l] * AV[((size_t)b * LL + l) * FP + t];
    cx[t] = fmaxf(acc, 0.f);
    __syncthreads();

    float air = mbih[t], aiz = mbih[FP + t], ain = mbih[2 * FP + t];
    float ahr = mbhh[t], ahz = mbhh[FP + t], ahn = mbhh[2 * FP + t];
    for (int i = 0; i < FP; ++i) {
        float c = cx[i], h = hh[i];
        air += c * MihT[i * 768 + t];
        aiz += c * MihT[i * 768 + FP + t];
        ain += c * MihT[i * 768 + 2 * FP + t];
        ahr += h * MhhT[i * 768 + t];
        ahz += h * MhhT[i * 768 + FP + t];
        ahn += h * MhhT[i * 768 + 2 * FP + t];
    }
    float r = 1.f / (1.f + expf(-(air + ahr)));
    float z = 1.f / (1.f + expf(-(aiz + ahz)));
    float n = tanhf(ain + r * ahn);
    float hn = (1.f - z) * n + z * hprev;

    molF[b * FP + t] = hn;
    o_unb[(size_t)(step + 1) * (BB * FP) + b * FP + t] = hn;
    o_mfv[(size_t)(step + 1) * (BB * FP) + b * FP + t] = fmaxf(hn, 0.f);
    if (step == TT - 1) o_molfeat[b * FP + t] = hn;
}

extern "C" void kernel_launch(void* const* d_in, const int* in_sizes, int n_in,
                              void* d_out, int out_size, void* d_ws, size_t ws_size,
                              hipStream_t stream) {
    const float* atom_list = (const float*)d_in[0];
    const float* bond_list = (const float*)d_in[1];
    const int*   adeg      = (const int*)d_in[2];
    const int*   bdeg      = (const int*)d_in[3];
    const float* amask     = (const float*)d_in[4];
    const float* atom_fc_W = (const float*)d_in[5];
    const float* atom_fc_b = (const float*)d_in[6];
    const float* nfc_W     = (const float*)d_in[7];
    const float* nfc_b     = (const float*)d_in[8];
    const float* gwih      = (const float*)d_in[9];
    const float* gwhh      = (const float*)d_in[10];
    const float* gbih      = (const float*)d_in[11];
    const float* gbhh      = (const float*)d_in[12];
    const float* alW       = (const float*)d_in[13];
    const float* alb       = (const float*)d_in[14];
    const float* atW       = (const float*)d_in[15];
    const float* atb       = (const float*)d_in[16];
    const float* mgwih     = (const float*)d_in[17];
    const float* mgwhh     = (const float*)d_in[18];
    const float* mgbih     = (const float*)d_in[19];
    const float* mgbhh     = (const float*)d_in[20];
    const float* malW      = (const float*)d_in[21];
    const float* malb      = (const float*)d_in[22];
    const float* matW      = (const float*)d_in[23];
    const float* matb      = (const float*)d_in[24];

    const size_t BLF = (size_t)BB * LL * FP;
    float* out = (float*)d_out;
    float* O0 = out;                                 // atom_feature / h (fp32)
    float* O1 = out + BLF;                           // afv (4,B,L,FP)
    float* O2 = O1 + 4 * BLF;                        // awv (3,B,L,K)
    float* O3 = O2 + (size_t)RR * BB * LL * KK;      // mfv
    float* O4 = O3 + (size_t)(TT + 1) * BB * FP;     // mol_unb
    float* O5 = O4 + (size_t)(TT + 1) * BB * FP;     // mawv
    float* O6 = O5 + (size_t)TT * BB * LL;           // mol_feature

    // ws layout
    float* ws = (float*)d_ws;
    short* XB   = (short*)ws;                        // BLF shorts: wn bf16
    short* XB2  = XB + BLF;                          // BLF shorts: ctx bf16
    short* HBb  = XB + 2 * BLF;                      // BLF shorts: h bf16
    float* AV   = ws;                                // BLF floats, aliases XB+XB2 (mol phase)
    float* rest = ws + (3 * BLF) / 2;
    float* Apre  = rest;                             // BLF floats
    float* SW    = Apre + BLF;                       // B*L floats
    float* MOLF  = SW + (size_t)BB * LL;
    float* WafcT = MOLF + (size_t)BB * FP;
    float* WnT   = WafcT + AA * FP;
    float* MWaT  = WnT + (AA + BDD) * FP;
    float* MihT  = MWaT + (size_t)FP * FP;
    float* MhhT  = MihT + (size_t)FP * 768;
    short* GW    = (short*)(MhhT + (size_t)FP * 768);   // RR*2*(8*48*512) shorts
    short* WaF   = GW + (size_t)RR * 2 * 8 * 48 * 512;  // RR*(8*16*512) shorts
    (void)ws_size; (void)in_sizes; (void)n_in; (void)out_size;

    auto tr = [&](const float* src, float* dst, int O, int I) {
        int n = O * I;
        k_transpose<<<(n + 255) / 256, 256, 0, stream>>>(src, dst, O, I);
    };
    tr(atom_fc_W, WafcT, FP, AA);
    tr(nfc_W, WnT, FP, AA + BDD);
    tr(matW, MWaT, FP, FP);
    tr(mgwih, MihT, 768, FP);
    tr(mgwhh, MhhT, 768, FP);

    const size_t wblk = (size_t)8 * 48 * 512;
    const size_t ablk = (size_t)8 * 16 * 512;
    for (int d = 0; d < RR; ++d) {
        k_prep_frag<<<(int)(wblk + 255) / 256, 256, 0, stream>>>(gwih + (size_t)d * 768 * FP, GW + (size_t)(d * 2 + 0) * wblk, 48);
        k_prep_frag<<<(int)(wblk + 255) / 256, 256, 0, stream>>>(gwhh + (size_t)d * 768 * FP, GW + (size_t)(d * 2 + 1) * wblk, 48);
        k_prep_frag<<<(int)(ablk + 255) / 256, 256, 0, stream>>>(atW + (size_t)d * FP * FP, WaF + (size_t)d * ablk, 16);
    }

    k_atom_fc8<<<BB * LL / 8, 256, 0, stream>>>(atom_list, WafcT, atom_fc_b, O1, O0, HBb);
    k_apre<<<BB * LL / 8, 256, 0, stream>>>(atom_list, WnT, nfc_b, Apre);

    for (int d = 0; d < RR; ++d) {
        const float* actPrev = (d == 0) ? O0 : (O1 + (size_t)d * BLF);
        k_awn<<<BB * LL / 4, 256, 0, stream>>>(d, actPrev, bond_list, Apre, adeg, bdeg,
                WnT, alW + (size_t)d * 2 * FP, alb + d,
                XB, SW, O2 + (size_t)d * BB * LL * KK);
        k_ctx_mfma<<<BB * LL / 32, 512, 0, stream>>>(XB, SW, WaF + (size_t)d * ablk,
                atb + (size_t)d * FP, XB2);
        k_gru_mfma<<<BB * LL / 32, 512, 0, stream>>>(XB2, HBb, O0,
                GW + (size_t)(d * 2 + 0) * wblk, GW + (size_t)(d * 2 + 1) * wblk,
                gbih + (size_t)d * 768, gbhh + (size_t)d * 768,
                O1 + (size_t)(d + 1) * BLF, HBb);
    }

    const float* actFin = O1 + (size_t)RR * BLF;
    k_mol_reduce<<<BB, 256, 0, stream>>>(O0, actFin, amask, O4, O3, MOLF);
    k_av<<<BB * LL / 8, 256, 0, stream>>>(actFin, MWaT, matb, AV);
    for (int st = 0; st < TT; ++st) {
        k_mol_step<<<BB, 256, 0, stream>>>(st, actFin, AV, MOLF, amask,
                malW, malb, MihT, MhhT, mgbih, mgbhh,
                O3, O4, O5, O6);
    }
}

// Round 4
// 774.892 us; speedup vs baseline: 3.6763x; 1.5112x over previous
//
#include <hip/hip_runtime.h>
#include <hip/hip_bf16.h>

// Dims
#define BB 256
#define LL 128
#define AA 39
#define BDD 10
#define KK 6
#define MM 256
#define FP 256
#define RR 3
#define TT 2

using short8 = __attribute__((ext_vector_type(8))) short;
using f32x4  = __attribute__((ext_vector_type(4))) float;

__device__ __forceinline__ short f2bf(float f) {
    union { float f; unsigned u; } v; v.f = f;
    unsigned u = v.u;
    u += 0x7fffu + ((u >> 16) & 1u);   // round-to-nearest-even
    return (short)(u >> 16);
}

// ---------------- transpose: dst[i*O+o] = src[o*I+i] ----------------
__global__ __launch_bounds__(256) void k_transpose(const float* __restrict__ src,
                                                   float* __restrict__ dst, int O, int I) {
    int idx = blockIdx.x * 256 + threadIdx.x;
    if (idx >= O * I) return;
    int o = idx / I, i = idx - o * I;
    dst[i * O + o] = src[idx];
}

// ---------------- pack a (n x 256) weight matrix into MFMA fragment-major bf16 ----
// out layout: [ks(8)][nt(NT)][lane(64)][j(8)]; n = nt*16+(lane&15), k = ks*32+(lane>>4)*8+j
__global__ __launch_bounds__(256) void k_prep_frag(const float* __restrict__ W,
                                                   short* __restrict__ out, int NT) {
    int idx = blockIdx.x * 256 + threadIdx.x;
    if (idx >= NT * 8 * 512) return;
    int j = idx & 7;
    int lane = (idx >> 3) & 63;
    int blk = idx >> 9;
    int nt = blk % NT;
    int ks = blk / NT;
    int n = nt * 16 + (lane & 15);
    int k = ks * 32 + (lane >> 4) * 8 + j;
    out[idx] = f2bf(W[(size_t)n * FP + k]);
}

// ---------------- atom fc (8 atoms/block): pre -> O1[0], relu -> h, bf16 h ------
__global__ __launch_bounds__(256) void k_atom_fc8(const float* __restrict__ atom_list,
                                                  const float* __restrict__ WafcT,
                                                  const float* __restrict__ bias,
                                                  float* __restrict__ out_pre,
                                                  float* __restrict__ hbuf,
                                                  short* __restrict__ hb16) {
    int g0 = blockIdx.x * 8;
    int t = threadIdx.x;
    __shared__ float x[8][AA];
    for (int i = t; i < 8 * AA; i += 256) x[i / AA][i % AA] = atom_list[(size_t)g0 * AA + i];
    __syncthreads();
    float acc[8];
    float bv = bias[t];
#pragma unroll
    for (int a = 0; a < 8; ++a) acc[a] = bv;
    for (int i = 0; i < AA; ++i) {
        float w = WafcT[i * FP + t];
#pragma unroll
        for (int a = 0; a < 8; ++a) acc[a] += x[a][i] * w;
    }
#pragma unroll
    for (int a = 0; a < 8; ++a) {
        size_t idx = (size_t)(g0 + a) * FP + t;
        out_pre[idx] = acc[a];
        float rl = fmaxf(acc[a], 0.f);
        hbuf[idx] = rl;
        hb16[idx] = f2bf(rl);
    }
}

// ---------------- A_pre = atom_list @ WnA^T + bn (atom part of neighbor fc) ----
__global__ __launch_bounds__(256) void k_apre(const float* __restrict__ atom_list,
                                              const float* __restrict__ WnT,
                                              const float* __restrict__ bn,
                                              float* __restrict__ Apre) {
    int g0 = blockIdx.x * 8;
    int t = threadIdx.x;
    __shared__ float x[8][AA];
    for (int i = t; i < 8 * AA; i += 256) x[i / AA][i % AA] = atom_list[(size_t)g0 * AA + i];
    __syncthreads();
    float acc[8];
    float bv = bn[t];
#pragma unroll
    for (int a = 0; a < 8; ++a) acc[a] = bv;
    for (int i = 0; i < AA; ++i) {
        float w = WnT[i * FP + t];
#pragma unroll
        for (int a = 0; a < 8; ++a) acc[a] += x[a][i] * w;
    }
#pragma unroll
    for (int a = 0; a < 8; ++a) Apre[(size_t)(g0 + a) * FP + t] = acc[a];
}

// ---------------- attention scores + weighted neighbor sum: one wave per atom ----
__global__ __launch_bounds__(256) void k_awn(int d,
        const float* __restrict__ actPrev,
        const float* __restrict__ bond_list,
        const float* __restrict__ Apre,
        const int* __restrict__ adeg, const int* __restrict__ bdeg,
        const float* __restrict__ WnT,
        const float* __restrict__ alignW, const float* __restrict__ alignBp,
        short* __restrict__ wn_out, float* __restrict__ sw_out,
        float* __restrict__ awv_out) {
    int wv = threadIdx.x >> 6, lane = threadIdx.x & 63;
    int a = blockIdx.x * 4 + wv;
    int b = a >> 7;

    float w0[4], w1[4];
#pragma unroll
    for (int q = 0; q < 4; ++q) { int c = lane + 64 * q; w0[q] = alignW[c]; w1[q] = alignW[FP + c]; }

    // self score
    float ss = 0.f;
#pragma unroll
    for (int q = 0; q < 4; ++q) ss += actPrev[(size_t)a * FP + lane + 64 * q] * w0[q];
#pragma unroll
    for (int off = 32; off; off >>= 1) ss += __shfl_xor(ss, off);
    float bias = alignBp[0];

    float nf[KK][4];
    float sc[KK];
    int jx[KK];
    for (int k = 0; k < KK; ++k) {
        int j = adeg[a * KK + k];
        jx[k] = j;
        size_t rb = ((size_t)(b * LL + j)) * FP;
        if (d == 0) {
            int bi = bdeg[a * KK + k];
            const float* blp = bond_list + ((size_t)b * MM + bi) * BDD;
            float bb[BDD];
#pragma unroll
            for (int i = 0; i < BDD; ++i) bb[i] = blp[i];
#pragma unroll
            for (int q = 0; q < 4; ++q) {
                int c = lane + 64 * q;
                float v = Apre[rb + c];
#pragma unroll
                for (int i = 0; i < BDD; ++i) v += bb[i] * WnT[(AA + i) * FP + c];
                nf[k][q] = fmaxf(v, 0.f);
            }
        } else {
#pragma unroll
            for (int q = 0; q < 4; ++q) nf[k][q] = actPrev[rb + lane + 64 * q];
        }
        float s2 = 0.f;
#pragma unroll
        for (int q = 0; q < 4; ++q) s2 += nf[k][q] * w1[q];
#pragma unroll
        for (int off = 32; off; off >>= 1) s2 += __shfl_xor(s2, off);
        float s = fmaxf(ss + s2 + bias, 0.f);
        if (j == LL - 1) s -= 9.0f;
        sc[k] = s;
    }

    // softmax over K (redundant across lanes)
    float m = sc[0];
#pragma unroll
    for (int k = 1; k < KK; ++k) m = fmaxf(m, sc[k]);
    float e[KK], den = 0.f;
#pragma unroll
    for (int k = 0; k < KK; ++k) { e[k] = expf(sc[k] - m); den += e[k]; }
    float aw[KK], sumaw = 0.f;
#pragma unroll
    for (int k = 0; k < KK; ++k) {
        aw[k] = (jx[k] == LL - 1) ? 0.f : e[k] / den;
        sumaw += aw[k];
    }
    if (lane < KK) {
        float v = aw[0];
#pragma unroll
        for (int k = 1; k < KK; ++k) if (lane == k) v = aw[k];
        awv_out[(size_t)a * KK + lane] = v;
    }
    if (lane == 0) sw_out[a] = sumaw;

#pragma unroll
    for (int q = 0; q < 4; ++q) {
        float w = 0.f;
#pragma unroll
        for (int k = 0; k < KK; ++k) w += aw[k] * nf[k][q];
        wn_out[(size_t)a * FP + lane + 64 * q] = f2bf(w);
    }
}

// ---------------- ctx = relu(WN @ Wa^T + sumaw*ab) via MFMA (32 atoms/block) ----
__global__ __launch_bounds__(512) void k_ctx_mfma(
        const short* __restrict__ XB,      // wn bf16
        const float* __restrict__ SW,
        const short* __restrict__ WaF,     // frag-major (8,16,64,8)
        const float* __restrict__ ab,
        short* __restrict__ ctx_out) {
    int t = threadIdx.x;
    int wave = t >> 6, lane = t & 63;
    int abase = blockIdx.x * 32 + (wave >> 2) * 16;
    int wn4 = wave & 3;
    int lr = lane & 15, lk = lane >> 4;

    f32x4 acc[4] = {};
    const short8* xrow = (const short8*)(XB + (size_t)(abase + lr) * FP);
    const short8* bw = (const short8*)WaF;

    for (int ks = 0; ks < 8; ++ks) {
        short8 ax = xrow[ks * 4 + lk];
#pragma unroll
        for (int sub = 0; sub < 4; ++sub) {
            int nt = wn4 * 4 + sub;
            acc[sub] = __builtin_amdgcn_mfma_f32_16x16x32_bf16(ax, bw[(size_t)(ks * 16 + nt) * 64 + lane], acc[sub], 0, 0, 0);
        }
    }
#pragma unroll
    for (int sub = 0; sub < 4; ++sub) {
        int c = wn4 * 64 + sub * 16 + lr;
        float abc = ab[c];
#pragma unroll
        for (int q = 0; q < 4; ++q) {
            int atom = abase + lk * 4 + q;
            float v = acc[sub][q] + SW[atom] * abc;
            ctx_out[(size_t)atom * FP + c] = f2bf(fmaxf(v, 0.f));
        }
    }
}

// ---------------- fused MFMA GRU v2: LDS-staged B, double-buffered phases ------
// 32 atoms/block, 8 waves. Per K-step two phases (ih, hh); each stages the
// 48-fragment (49152 B) B-slice for the NEXT phase via global_load_lds while
// computing the current one from LDS. B L2 traffic: once per block (not per wave).
__global__ __launch_bounds__(512) void k_gru_mfma(
        const short* __restrict__ XB,     // ctx bf16
        const short* __restrict__ HBl,    // h bf16 (read)
        float* __restrict__ hbuf,         // h fp32 (read old, write new)
        const short* __restrict__ Bih,    // frag-major (8,48,64,8)
        const short* __restrict__ Bhh,
        const float* __restrict__ bih, const float* __restrict__ bhh,
        float* __restrict__ act_out,
        short* __restrict__ HB_out) {
    __shared__ short lds[2][24576];       // 2 x 49152 B
    const int t = threadIdx.x;
    const int wave = t >> 6, lane = t & 63;
    const int abase = blockIdx.x * 32 + (wave >> 2) * 16;
    const int wn = wave & 3;
    const int lr = lane & 15, lk = lane >> 4;

    f32x4 acc_i[12] = {};   // [g*4+sub]
    f32x4 acc_h[12] = {};

    const short8* xrow = (const short8*)(XB + (size_t)(abase + lr) * FP);
    const short8* hrow = (const short8*)(HBl + (size_t)(abase + lr) * FP);

#define STAGE(buf, src) do { \
    const short* _s = (src); \
    _Pragma("unroll") \
    for (int c = 0; c < 6; ++c) { \
        const short* gp = _s + c * 4096 + wave * 512 + lane * 8; \
        __builtin_amdgcn_global_load_lds( \
            (const __attribute__((address_space(1))) void*)gp, \
            (__attribute__((address_space(3))) void*)(&lds[buf][c * 4096 + wave * 512]), \
            16, 0, 0); \
    } } while (0)

#define COMPUTE(buf, accarr, a8) do { \
    _Pragma("unroll") \
    for (int i = 0; i < 12; ++i) { \
        int nt = (i >> 2) * 16 + wn * 4 + (i & 3); \
        short8 bf = *(const short8*)(&lds[buf][nt * 512 + lane * 8]); \
        accarr[i] = __builtin_amdgcn_mfma_f32_16x16x32_bf16(a8, bf, accarr[i], 0, 0, 0); \
    } } while (0)

    // prologue: stage phase 0 (ks=0, ih) into buf 0
    STAGE(0, Bih);

    for (int ks = 0; ks < 8; ++ks) {
        short8 ax = xrow[ks * 4 + lk];
        short8 ah = hrow[ks * 4 + lk];
        // phase 2ks (ih), data in buf0. __syncthreads drains the staging loads.
        __syncthreads();
        STAGE(1, Bhh + (size_t)ks * 24576);     // stage next phase (hh) during compute
        COMPUTE(0, acc_i, ax);
        // phase 2ks+1 (hh), data in buf1.
        __syncthreads();
        if (ks < 7) STAGE(0, Bih + (size_t)(ks + 1) * 24576);
        COMPUTE(1, acc_h, ah);
    }
#undef STAGE
#undef COMPUTE

    __syncthreads();   // all HBl reads complete before HB_out writes

#pragma unroll
    for (int sub = 0; sub < 4; ++sub) {
        int c = wn * 64 + sub * 16 + lr;
        float bir = bih[c], biz = bih[FP + c], bin_ = bih[2 * FP + c];
        float bhr = bhh[c], bhz = bhh[FP + c], bhn = bhh[2 * FP + c];
#pragma unroll
        for (int q = 0; q < 4; ++q) {
            int atom = abase + lk * 4 + q;
            size_t idx = (size_t)atom * FP + c;
            float hold = hbuf[idx];
            float r = 1.f / (1.f + expf(-(acc_i[0 * 4 + sub][q] + bir + acc_h[0 * 4 + sub][q] + bhr)));
            float z = 1.f / (1.f + expf(-(acc_i[1 * 4 + sub][q] + biz + acc_h[1 * 4 + sub][q] + bhz)));
            float n = tanhf(acc_i[2 * 4 + sub][q] + bin_ + r * (acc_h[2 * 4 + sub][q] + bhn));
            float hn = (1.f - z) * n + z * hold;
            hbuf[idx] = hn;
            act_out[idx] = fmaxf(hn, 0.f);
            HB_out[idx] = f2bf(hn);
        }
    }
}

// ---------------- mol reductions ----------------
__global__ __launch_bounds__(256) void k_mol_reduce(const float* __restrict__ hbuf,
                                                    const float* __restrict__ act,
                                                    const float* __restrict__ mask,
                                                    float* __restrict__ o_unb0,
                                                    float* __restrict__ o_mfv0,
                                                    float* __restrict__ molF) {
    int b = blockIdx.x, t = threadIdx.x;
    float s1 = 0.f, s2 = 0.f;
    for (int l = 0; l < LL; ++l) {
        float mk = mask[b * LL + l];
        s1 += hbuf[((size_t)b * LL + l) * FP + t] * mk;
        s2 += act[((size_t)b * LL + l) * FP + t] * mk;
    }
    o_unb0[b * FP + t] = s1;
    o_mfv0[b * FP + t] = s2;
    molF[b * FP + t] = s2;
}

// ---------------- AV = act @ mol_attend_W.T + b ----------------
__global__ __launch_bounds__(256) void k_av(const float* __restrict__ act,
                                            const float* __restrict__ MWaT,
                                            const float* __restrict__ mab,
                                            float* __restrict__ AV) {
    int g0 = blockIdx.x * 8;
    int t = threadIdx.x;
    __shared__ float xs[8][FP];
    for (int a = 0; a < 8; ++a) xs[a][t] = act[(size_t)(g0 + a) * FP + t];
    __syncthreads();
    float acc[8];
    float bb2 = mab[t];
#pragma unroll
    for (int a = 0; a < 8; ++a) acc[a] = bb2;
    for (int i = 0; i < FP; ++i) {
        float w = MWaT[i * FP + t];
#pragma unroll
        for (int a = 0; a < 8; ++a) acc[a] += xs[a][i] * w;
    }
    for (int a = 0; a < 8; ++a) AV[(size_t)(g0 + a) * FP + t] = acc[a];
}

// ---------------- mol attention + mol GRU ----------------
__global__ __launch_bounds__(256) void k_mol_step(int step,
        const float* __restrict__ act,
        const float* __restrict__ AV,
        float* __restrict__ molF,
        const float* __restrict__ mask,
        const float* __restrict__ mAw, const float* __restrict__ mAb,
        const float* __restrict__ MihT, const float* __restrict__ MhhT,
        const float* __restrict__ mbih, const float* __restrict__ mbhh,
        float* __restrict__ o_mfv, float* __restrict__ o_unb,
        float* __restrict__ o_mawv, float* __restrict__ o_molfeat) {
    int b = blockIdx.x, t = threadIdx.x;
    int wave = t >> 6, lane = t & 63;
    __shared__ float am[FP], hh[FP], cx[FP];
    __shared__ float S2[LL], mw[LL];
    __shared__ float red[4];

    float hprev = molF[b * FP + t];
    hh[t] = hprev;
    am[t] = fmaxf(hprev, 0.f);
    __syncthreads();

    float v = am[t] * mAw[t];
#pragma unroll
    for (int off = 32; off >= 1; off >>= 1) v += __shfl_xor(v, off);
    if (lane == 0) red[wave] = v;
    __syncthreads();
    float s_self = red[0] + red[1] + red[2] + red[3];

    for (int l = wave; l < LL; l += 4) {
        float v2 = 0.f;
#pragma unroll
        for (int q = 0; q < 4; ++q) {
            int i = lane + 64 * q;
            v2 += act[((size_t)b * LL + l) * FP + i] * mAw[FP + i];
        }
#pragma unroll
        for (int off = 32; off >= 1; off >>= 1) v2 += __shfl_xor(v2, off);
        if (lane == 0) S2[l] = v2;
    }
    __syncthreads();

    if (t < LL) {
        float s = fmaxf(s_self + S2[t] + mAb[0], 0.f);
        if (mask[b * LL + t] == 0.f) s += -9e8f;
        S2[t] = s;
    }
    __syncthreads();

    float m = -1e30f;
    for (int l = 0; l < LL; ++l) m = fmaxf(m, S2[l]);
    float den = 0.f;
    for (int l = 0; l < LL; ++l) den += expf(S2[l] - m);
    if (t < LL) {
        float w = expf(S2[t] - m) / den * mask[b * LL + t];
        mw[t] = w;
        o_mawv[(size_t)step * (BB * LL) + b * LL + t] = w;
    }
    __syncthreads();

    float acc = 0.f;
    for (int l = 0; l < LL; ++l) acc += mw[l] * AV[((size_t)b * LL + l) * FP + t];
    cx[t] = fmaxf(acc, 0.f);
    __syncthreads();

    float air = mbih[t], aiz = mbih[FP + t], ain = mbih[2 * FP + t];
    float ahr = mbhh[t], ahz = mbhh[FP + t], ahn = mbhh[2 * FP + t];
    for (int i = 0; i < FP; ++i) {
        float c = cx[i], h = hh[i];
        air += c * MihT[i * 768 + t];
        aiz += c * MihT[i * 768 + FP + t];
        ain += c * MihT[i * 768 + 2 * FP + t];
        ahr += h * MhhT[i * 768 + t];
        ahz += h * MhhT[i * 768 + FP + t];
        ahn += h * MhhT[i * 768 + 2 * FP + t];
    }
    float r = 1.f / (1.f + expf(-(air + ahr)));
    float z = 1.f / (1.f + expf(-(aiz + ahz)));
    float n = tanhf(ain + r * ahn);
    float hn = (1.f - z) * n + z * hprev;

    molF[b * FP + t] = hn;
    o_unb[(size_t)(step + 1) * (BB * FP) + b * FP + t] = hn;
    o_mfv[(size_t)(step + 1) * (BB * FP) + b * FP + t] = fmaxf(hn, 0.f);
    if (step == TT - 1) o_molfeat[b * FP + t] = hn;
}

extern "C" void kernel_launch(void* const* d_in, const int* in_sizes, int n_in,
                              void* d_out, int out_size, void* d_ws, size_t ws_size,
                              hipStream_t stream) {
    const float* atom_list = (const float*)d_in[0];
    const float* bond_list = (const float*)d_in[1];
    const int*   adeg      = (const int*)d_in[2];
    const int*   bdeg      = (const int*)d_in[3];
    const float* amask     = (const float*)d_in[4];
    const float* atom_fc_W = (const float*)d_in[5];
    const float* atom_fc_b = (const float*)d_in[6];
    const float* nfc_W     = (const float*)d_in[7];
    const float* nfc_b     = (const float*)d_in[8];
    const float* gwih      = (const float*)d_in[9];
    const float* gwhh      = (const float*)d_in[10];
    const float* gbih      = (const float*)d_in[11];
    const float* gbhh      = (const float*)d_in[12];
    const float* alW       = (const float*)d_in[13];
    const float* alb       = (const float*)d_in[14];
    const float* atW       = (const float*)d_in[15];
    const float* atb       = (const float*)d_in[16];
    const float* mgwih     = (const float*)d_in[17];
    const float* mgwhh     = (const float*)d_in[18];
    const float* mgbih     = (const float*)d_in[19];
    const float* mgbhh     = (const float*)d_in[20];
    const float* malW      = (const float*)d_in[21];
    const float* malb      = (const float*)d_in[22];
    const float* matW      = (const float*)d_in[23];
    const float* matb      = (const float*)d_in[24];

    const size_t BLF = (size_t)BB * LL * FP;
    float* out = (float*)d_out;
    float* O0 = out;                                 // atom_feature / h (fp32)
    float* O1 = out + BLF;                           // afv (4,B,L,FP)
    float* O2 = O1 + 4 * BLF;                        // awv (3,B,L,K)
    float* O3 = O2 + (size_t)RR * BB * LL * KK;      // mfv
    float* O4 = O3 + (size_t)(TT + 1) * BB * FP;     // mol_unb
    float* O5 = O4 + (size_t)(TT + 1) * BB * FP;     // mawv
    float* O6 = O5 + (size_t)TT * BB * LL;           // mol_feature

    // ws layout
    float* ws = (float*)d_ws;
    short* XB   = (short*)ws;                        // BLF shorts: wn bf16
    short* XB2  = XB + BLF;                          // BLF shorts: ctx bf16
    short* HBb  = XB + 2 * BLF;                      // BLF shorts: h bf16
    float* AV   = ws;                                // BLF floats, aliases XB+XB2 (mol phase)
    float* rest = ws + (3 * BLF) / 2;
    float* Apre  = rest;                             // BLF floats
    float* SW    = Apre + BLF;                       // B*L floats
    float* MOLF  = SW + (size_t)BB * LL;
    float* WafcT = MOLF + (size_t)BB * FP;
    float* WnT   = WafcT + AA * FP;
    float* MWaT  = WnT + (AA + BDD) * FP;
    float* MihT  = MWaT + (size_t)FP * FP;
    float* MhhT  = MihT + (size_t)FP * 768;
    short* GW    = (short*)(MhhT + (size_t)FP * 768);   // RR*2*(8*48*512) shorts
    short* WaF   = GW + (size_t)RR * 2 * 8 * 48 * 512;  // RR*(8*16*512) shorts
    (void)ws_size; (void)in_sizes; (void)n_in; (void)out_size;

    auto tr = [&](const float* src, float* dst, int O, int I) {
        int n = O * I;
        k_transpose<<<(n + 255) / 256, 256, 0, stream>>>(src, dst, O, I);
    };
    tr(atom_fc_W, WafcT, FP, AA);
    tr(nfc_W, WnT, FP, AA + BDD);
    tr(matW, MWaT, FP, FP);
    tr(mgwih, MihT, 768, FP);
    tr(mgwhh, MhhT, 768, FP);

    const size_t wblk = (size_t)8 * 48 * 512;
    const size_t ablk = (size_t)8 * 16 * 512;
    for (int d = 0; d < RR; ++d) {
        k_prep_frag<<<(int)(wblk + 255) / 256, 256, 0, stream>>>(gwih + (size_t)d * 768 * FP, GW + (size_t)(d * 2 + 0) * wblk, 48);
        k_prep_frag<<<(int)(wblk + 255) / 256, 256, 0, stream>>>(gwhh + (size_t)d * 768 * FP, GW + (size_t)(d * 2 + 1) * wblk, 48);
        k_prep_frag<<<(int)(ablk + 255) / 256, 256, 0, stream>>>(atW + (size_t)d * FP * FP, WaF + (size_t)d * ablk, 16);
    }

    k_atom_fc8<<<BB * LL / 8, 256, 0, stream>>>(atom_list, WafcT, atom_fc_b, O1, O0, HBb);
    k_apre<<<BB * LL / 8, 256, 0, stream>>>(atom_list, WnT, nfc_b, Apre);

    for (int d = 0; d < RR; ++d) {
        const float* actPrev = (d == 0) ? O0 : (O1 + (size_t)d * BLF);
        k_awn<<<BB * LL / 4, 256, 0, stream>>>(d, actPrev, bond_list, Apre, adeg, bdeg,
                WnT, alW + (size_t)d * 2 * FP, alb + d,
                XB, SW, O2 + (size_t)d * BB * LL * KK);
        k_ctx_mfma<<<BB * LL / 32, 512, 0, stream>>>(XB, SW, WaF + (size_t)d * ablk,
                atb + (size_t)d * FP, XB2);
        k_gru_mfma<<<BB * LL / 32, 512, 0, stream>>>(XB2, HBb, O0,
                GW + (size_t)(d * 2 + 0) * wblk, GW + (size_t)(d * 2 + 1) * wblk,
                gbih + (size_t)d * 768, gbhh + (size_t)d * 768,
                O1 + (size_t)(d + 1) * BLF, HBb);
    }

    const float* actFin = O1 + (size_t)RR * BLF;
    k_mol_reduce<<<BB, 256, 0, stream>>>(O0, actFin, amask, O4, O3, MOLF);
    k_av<<<BB * LL / 8, 256, 0, stream>>>(actFin, MWaT, matb, AV);
    for (int st = 0; st < TT; ++st) {
        k_mol_step<<<BB, 256, 0, stream>>>(st, actFin, AV, MOLF, amask,
                malW, malb, MihT, MhhT, mgbih, mgbhh,
                O3, O4, O5, O6);
    }
}

// Round 5
// 718.335 us; speedup vs baseline: 3.9657x; 1.0787x over previous
//
#include <hip/hip_runtime.h>
#include <hip/hip_bf16.h>

// Dims
#define BB 256
#define LL 128
#define AA 39
#define BDD 10
#define KK 6
#define MM 256
#define FP 256
#define RR 3
#define TT 2

using short8  = __attribute__((ext_vector_type(8))) short;
using short4v = __attribute__((ext_vector_type(4))) short;
using f32x4   = __attribute__((ext_vector_type(4))) float;
using f32x2   = __attribute__((ext_vector_type(2))) float;

__device__ __forceinline__ short f2bf(float f) {
    union { float f; unsigned u; } v; v.f = f;
    unsigned u = v.u;
    u += 0x7fffu + ((u >> 16) & 1u);   // round-to-nearest-even
    return (short)(u >> 16);
}
__device__ __forceinline__ float bf2f(short s) {
    union { unsigned u; float f; } v; v.u = ((unsigned)(unsigned short)s) << 16;
    return v.f;
}
__device__ __forceinline__ float wred64(float v) {
#pragma unroll
    for (int off = 32; off >= 1; off >>= 1) v += __shfl_xor(v, off);
    return v;
}

// ---------------- transpose: dst[i*O+o] = src[o*I+i] ----------------
__global__ __launch_bounds__(256) void k_transpose(const float* __restrict__ src,
                                                   float* __restrict__ dst, int O, int I) {
    int idx = blockIdx.x * 256 + threadIdx.x;
    if (idx >= O * I) return;
    int o = idx / I, i = idx - o * I;
    dst[i * O + o] = src[idx];
}

// ---------------- pack a (n x 256) weight matrix into MFMA fragment-major bf16 ----
__global__ __launch_bounds__(256) void k_prep_frag(const float* __restrict__ W,
                                                   short* __restrict__ out, int NT) {
    int idx = blockIdx.x * 256 + threadIdx.x;
    if (idx >= NT * 8 * 512) return;
    int j = idx & 7;
    int lane = (idx >> 3) & 63;
    int blk = idx >> 9;
    int nt = blk % NT;
    int ks = blk / NT;
    int n = nt * 16 + (lane & 15);
    int k = ks * 32 + (lane >> 4) * 8 + j;
    out[idx] = f2bf(W[(size_t)n * FP + k]);
}

// ---------------- atom fc (8 atoms/block) ----------------
__global__ __launch_bounds__(256) void k_atom_fc8(const float* __restrict__ atom_list,
                                                  const float* __restrict__ WafcT,
                                                  const float* __restrict__ bias,
                                                  float* __restrict__ out_pre,
                                                  float* __restrict__ hbuf,
                                                  short* __restrict__ hb16) {
    int g0 = blockIdx.x * 8;
    int t = threadIdx.x;
    __shared__ float x[8][AA];
    for (int i = t; i < 8 * AA; i += 256) x[i / AA][i % AA] = atom_list[(size_t)g0 * AA + i];
    __syncthreads();
    float acc[8];
    float bv = bias[t];
#pragma unroll
    for (int a = 0; a < 8; ++a) acc[a] = bv;
    for (int i = 0; i < AA; ++i) {
        float w = WafcT[i * FP + t];
#pragma unroll
        for (int a = 0; a < 8; ++a) acc[a] += x[a][i] * w;
    }
#pragma unroll
    for (int a = 0; a < 8; ++a) {
        size_t idx = (size_t)(g0 + a) * FP + t;
        out_pre[idx] = acc[a];
        float rl = fmaxf(acc[a], 0.f);
        hbuf[idx] = rl;
        hb16[idx] = f2bf(rl);   // h0 = relu(pre); also serves as ACTB for d=0
    }
}

// ---------------- ApreB = bf16(atom_list @ WnA^T + bn) ----------------
__global__ __launch_bounds__(256) void k_apre(const float* __restrict__ atom_list,
                                              const float* __restrict__ WnT,
                                              const float* __restrict__ bn,
                                              short* __restrict__ ApreB) {
    int g0 = blockIdx.x * 8;
    int t = threadIdx.x;
    __shared__ float x[8][AA];
    for (int i = t; i < 8 * AA; i += 256) x[i / AA][i % AA] = atom_list[(size_t)g0 * AA + i];
    __syncthreads();
    float acc[8];
    float bv = bn[t];
#pragma unroll
    for (int a = 0; a < 8; ++a) acc[a] = bv;
    for (int i = 0; i < AA; ++i) {
        float w = WnT[i * FP + t];
#pragma unroll
        for (int a = 0; a < 8; ++a) acc[a] += x[a][i] * w;
    }
#pragma unroll
    for (int a = 0; a < 8; ++a) ApreB[(size_t)(g0 + a) * FP + t] = f2bf(acc[a]);
}

// ---------------- attention: per-molecule LDS-staged gather ----------------
// 1 block / molecule, 1024 threads (16 waves), wave handles 8 atoms.
// snb = staged neighbor source (ACTB for d>0, ApreB for d0), 64KB bf16.
template<int IS_D0>
__global__ __launch_bounds__(1024) void k_awn2(
        const short* __restrict__ ACTB,     // relu'd act bf16 (self dots)
        const short* __restrict__ SRC,      // neighbor source to stage
        const float* __restrict__ bond_list,
        const int* __restrict__ adeg, const int* __restrict__ bdeg,
        const float* __restrict__ WnT,      // bond rows AA..AA+BDD-1 (d0 only)
        const float* __restrict__ alignW, const float* __restrict__ alignBp,
        short* __restrict__ wn_out, float* __restrict__ sw_out,
        float* __restrict__ awv_out) {
    __shared__ short snb[LL * FP];          // 64 KB
    const int b = blockIdx.x;
    const int t = threadIdx.x;
    const int wave = t >> 6, lane = t & 63;

    // stage molecule slab (contiguous 64KB) via global_load_lds width-16
    {
        const char* src = (const char*)(SRC + (size_t)b * LL * FP);
#pragma unroll
        for (int it = 0; it < 4; ++it) {
            int off = it * 16384 + wave * 1024 + lane * 16;
            __builtin_amdgcn_global_load_lds(
                (const __attribute__((address_space(1))) void*)(src + off),
                (__attribute__((address_space(3))) void*)((char*)snb + it * 16384 + wave * 1024),
                16, 0, 0);
        }
    }

    // per-lane align weights (cols lane*4 .. lane*4+3)
    f32x4 w0 = *(const f32x4*)(alignW + lane * 4);
    f32x4 w1 = *(const f32x4*)(alignW + FP + lane * 4);
    float bias = alignBp[0];

    float wnt[IS_D0 ? BDD : 1][4];
    if constexpr (IS_D0) {
#pragma unroll
        for (int i = 0; i < BDD; ++i) {
            f32x4 v = *(const f32x4*)(WnT + (AA + i) * FP + lane * 4);
#pragma unroll
            for (int q = 0; q < 4; ++q) wnt[i][q] = v[q];
        }
    }

    __syncthreads();   // staging complete

#pragma unroll
    for (int ai = 0; ai < 8; ++ai) {
        const int al = wave * 8 + ai;
        const int ga = b * LL + al;

        // self score: 8B global read of ACTB row
        short4v sv = *(const short4v*)(ACTB + (size_t)ga * FP + lane * 4);
        float ss = wred64(bf2f(sv[0]) * w0[0] + bf2f(sv[1]) * w0[1] +
                          bf2f(sv[2]) * w0[2] + bf2f(sv[3]) * w0[3]);

        int jx[KK];
#pragma unroll
        for (int k = 0; k < KK; ++k) jx[k] = adeg[ga * KK + k];

        float nf[KK][4];
        float sc[KK];
#pragma unroll
        for (int k = 0; k < KK; ++k) {
            short4v nv = *(const short4v*)(snb + jx[k] * FP + lane * 4);
            float f0 = bf2f(nv[0]), f1 = bf2f(nv[1]), f2 = bf2f(nv[2]), f3 = bf2f(nv[3]);
            if constexpr (IS_D0) {
                int bi = bdeg[ga * KK + k];
                const float* bp = bond_list + ((size_t)b * MM + bi) * BDD;
                float bb[BDD];
#pragma unroll
                for (int i = 0; i < 5; ++i) {
                    f32x2 v2 = *(const f32x2*)(bp + 2 * i);
                    bb[2 * i] = v2[0]; bb[2 * i + 1] = v2[1];
                }
                float b0 = 0.f, b1 = 0.f, b2 = 0.f, b3 = 0.f;
#pragma unroll
                for (int i = 0; i < BDD; ++i) {
                    b0 += bb[i] * wnt[i][0]; b1 += bb[i] * wnt[i][1];
                    b2 += bb[i] * wnt[i][2]; b3 += bb[i] * wnt[i][3];
                }
                f0 = fmaxf(f0 + b0, 0.f); f1 = fmaxf(f1 + b1, 0.f);
                f2 = fmaxf(f2 + b2, 0.f); f3 = fmaxf(f3 + b3, 0.f);
            }
            nf[k][0] = f0; nf[k][1] = f1; nf[k][2] = f2; nf[k][3] = f3;
            float s2 = wred64(f0 * w1[0] + f1 * w1[1] + f2 * w1[2] + f3 * w1[3]);
            float s = fmaxf(ss + s2 + bias, 0.f);
            if (jx[k] == LL - 1) s -= 9.0f;
            sc[k] = s;
        }

        // softmax over K (identical in all lanes)
        float m = sc[0];
#pragma unroll
        for (int k = 1; k < KK; ++k) m = fmaxf(m, sc[k]);
        float e[KK], den = 0.f;
#pragma unroll
        for (int k = 0; k < KK; ++k) { e[k] = expf(sc[k] - m); den += e[k]; }
        float aw[KK], sumaw = 0.f;
#pragma unroll
        for (int k = 0; k < KK; ++k) {
            aw[k] = (jx[k] == LL - 1) ? 0.f : e[k] / den;
            sumaw += aw[k];
        }
        if (lane < KK) {
            float av = aw[0];
#pragma unroll
            for (int k = 1; k < KK; ++k) if (lane == k) av = aw[k];
            awv_out[(size_t)ga * KK + lane] = av;
        }
        if (lane == 0) sw_out[ga] = sumaw;

        // weighted neighbor sum -> bf16x4 store
        short4v wo;
#pragma unroll
        for (int q = 0; q < 4; ++q) {
            float w = 0.f;
#pragma unroll
            for (int k = 0; k < KK; ++k) w += aw[k] * nf[k][q];
            wo[q] = f2bf(w);
        }
        *(short4v*)(wn_out + (size_t)ga * FP + lane * 4) = wo;
    }
}

// ---------------- ctx = relu(WN @ Wa^T + sumaw*ab) via MFMA (32 atoms/block) ----
__global__ __launch_bounds__(512) void k_ctx_mfma(
        const short* __restrict__ XB,      // wn bf16
        const float* __restrict__ SW,
        const short* __restrict__ WaF,     // frag-major (8,16,64,8)
        const float* __restrict__ ab,
        short* __restrict__ ctx_out) {
    int t = threadIdx.x;
    int wave = t >> 6, lane = t & 63;
    int abase = blockIdx.x * 32 + (wave >> 2) * 16;
    int wn4 = wave & 3;
    int lr = lane & 15, lk = lane >> 4;

    f32x4 acc[4] = {};
    const short8* xrow = (const short8*)(XB + (size_t)(abase + lr) * FP);
    const short8* bw = (const short8*)WaF;

    for (int ks = 0; ks < 8; ++ks) {
        short8 ax = xrow[ks * 4 + lk];
#pragma unroll
        for (int sub = 0; sub < 4; ++sub) {
            int nt = wn4 * 4 + sub;
            acc[sub] = __builtin_amdgcn_mfma_f32_16x16x32_bf16(ax, bw[(size_t)(ks * 16 + nt) * 64 + lane], acc[sub], 0, 0, 0);
        }
    }
#pragma unroll
    for (int sub = 0; sub < 4; ++sub) {
        int c = wn4 * 64 + sub * 16 + lr;
        float abc = ab[c];
#pragma unroll
        for (int q = 0; q < 4; ++q) {
            int atom = abase + lk * 4 + q;
            float v = acc[sub][q] + SW[atom] * abc;
            ctx_out[(size_t)atom * FP + c] = f2bf(fmaxf(v, 0.f));
        }
    }
}

// ---------------- fused MFMA GRU: LDS-staged B, double-buffered phases ------
__global__ __launch_bounds__(512) void k_gru_mfma(
        const short* __restrict__ XB,     // ctx bf16
        const short* __restrict__ HBl,    // h bf16 (read)
        float* __restrict__ hbuf,         // h fp32 (read old, write new)
        const short* __restrict__ Bih,    // frag-major (8,48,64,8)
        const short* __restrict__ Bhh,
        const float* __restrict__ bih, const float* __restrict__ bhh,
        float* __restrict__ act_out,
        short* __restrict__ HB_out,
        short* __restrict__ ACT_out) {    // bf16 relu(h)
    __shared__ short lds[2][24576];       // 2 x 49152 B
    const int t = threadIdx.x;
    const int wave = t >> 6, lane = t & 63;
    const int abase = blockIdx.x * 32 + (wave >> 2) * 16;
    const int wn = wave & 3;
    const int lr = lane & 15, lk = lane >> 4;

    f32x4 acc_i[12] = {};
    f32x4 acc_h[12] = {};

    const short8* xrow = (const short8*)(XB + (size_t)(abase + lr) * FP);
    const short8* hrow = (const short8*)(HBl + (size_t)(abase + lr) * FP);

#define STAGE(buf, src) do { \
    const short* _s = (src); \
    _Pragma("unroll") \
    for (int c = 0; c < 6; ++c) { \
        const short* gp = _s + c * 4096 + wave * 512 + lane * 8; \
        __builtin_amdgcn_global_load_lds( \
            (const __attribute__((address_space(1))) void*)gp, \
            (__attribute__((address_space(3))) void*)(&lds[buf][c * 4096 + wave * 512]), \
            16, 0, 0); \
    } } while (0)

#define COMPUTE(buf, accarr, a8) do { \
    _Pragma("unroll") \
    for (int i = 0; i < 12; ++i) { \
        int nt = (i >> 2) * 16 + wn * 4 + (i & 3); \
        short8 bf = *(const short8*)(&lds[buf][nt * 512 + lane * 8]); \
        accarr[i] = __builtin_amdgcn_mfma_f32_16x16x32_bf16(a8, bf, accarr[i], 0, 0, 0); \
    } } while (0)

    STAGE(0, Bih);

    for (int ks = 0; ks < 8; ++ks) {
        short8 ax = xrow[ks * 4 + lk];
        short8 ah = hrow[ks * 4 + lk];
        __syncthreads();
        STAGE(1, Bhh + (size_t)ks * 24576);
        COMPUTE(0, acc_i, ax);
        __syncthreads();
        if (ks < 7) STAGE(0, Bih + (size_t)(ks + 1) * 24576);
        COMPUTE(1, acc_h, ah);
    }
#undef STAGE
#undef COMPUTE

    __syncthreads();   // all HBl reads complete before HB_out writes

#pragma unroll
    for (int sub = 0; sub < 4; ++sub) {
        int c = wn * 64 + sub * 16 + lr;
        float bir = bih[c], biz = bih[FP + c], bin_ = bih[2 * FP + c];
        float bhr = bhh[c], bhz = bhh[FP + c], bhn = bhh[2 * FP + c];
#pragma unroll
        for (int q = 0; q < 4; ++q) {
            int atom = abase + lk * 4 + q;
            size_t idx = (size_t)atom * FP + c;
            float hold = hbuf[idx];
            float r = 1.f / (1.f + expf(-(acc_i[0 * 4 + sub][q] + bir + acc_h[0 * 4 + sub][q] + bhr)));
            float z = 1.f / (1.f + expf(-(acc_i[1 * 4 + sub][q] + biz + acc_h[1 * 4 + sub][q] + bhz)));
            float n = tanhf(acc_i[2 * 4 + sub][q] + bin_ + r * (acc_h[2 * 4 + sub][q] + bhn));
            float hn = (1.f - z) * n + z * hold;
            float rl = fmaxf(hn, 0.f);
            hbuf[idx] = hn;
            act_out[idx] = rl;
            HB_out[idx] = f2bf(hn);
            ACT_out[idx] = f2bf(rl);
        }
    }
}

// ---------------- mol reductions ----------------
__global__ __launch_bounds__(256) void k_mol_reduce(const float* __restrict__ hbuf,
                                                    const float* __restrict__ act,
                                                    const float* __restrict__ mask,
                                                    float* __restrict__ o_unb0,
                                                    float* __restrict__ o_mfv0,
                                                    float* __restrict__ molF) {
    int b = blockIdx.x, t = threadIdx.x;
    float s1 = 0.f, s2 = 0.f;
    for (int l = 0; l < LL; ++l) {
        float mk = mask[b * LL + l];
        s1 += hbuf[((size_t)b * LL + l) * FP + t] * mk;
        s2 += act[((size_t)b * LL + l) * FP + t] * mk;
    }
    o_unb0[b * FP + t] = s1;
    o_mfv0[b * FP + t] = s2;
    molF[b * FP + t] = s2;
}

// ---------------- AV = act @ mol_attend_W.T + b ----------------
__global__ __launch_bounds__(256) void k_av(const float* __restrict__ act,
                                            const float* __restrict__ MWaT,
                                            const float* __restrict__ mab,
                                            float* __restrict__ AV) {
    int g0 = blockIdx.x * 8;
    int t = threadIdx.x;
    __shared__ float xs[8][FP];
    for (int a = 0; a < 8; ++a) xs[a][t] = act[(size_t)(g0 + a) * FP + t];
    __syncthreads();
    float acc[8];
    float bb2 = mab[t];
#pragma unroll
    for (int a = 0; a < 8; ++a) acc[a] = bb2;
    for (int i = 0; i < FP; ++i) {
        float w = MWaT[i * FP + t];
#pragma unroll
        for (int a = 0; a < 8; ++a) acc[a] += xs[a][i] * w;
    }
    for (int a = 0; a < 8; ++a) AV[(size_t)(g0 + a) * FP + t] = acc[a];
}

// ---------------- mol attention + mol GRU ----------------
__global__ __launch_bounds__(256) void k_mol_step(int step,
        const float* __restrict__ act,
        const float* __restrict__ AV,
        float* __restrict__ molF,
        const float* __restrict__ mask,
        const float* __restrict__ mAw, const float* __restrict__ mAb,
        const float* __restrict__ MihT, const float* __restrict__ MhhT,
        const float* __restrict__ mbih, const float* __restrict__ mbhh,
        float* __restrict__ o_mfv, float* __restrict__ o_unb,
        float* __restrict__ o_mawv, float* __restrict__ o_molfeat) {
    int b = blockIdx.x, t = threadIdx.x;
    int wave = t >> 6, lane = t & 63;
    __shared__ float am[FP], hh[FP], cx[FP];
    __shared__ float S2[LL], mw[LL];
    __shared__ float red[4];

    float hprev = molF[b * FP + t];
    hh[t] = hprev;
    am[t] = fmaxf(hprev, 0.f);
    __syncthreads();

    float v = am[t] * mAw[t];
#pragma unroll
    for (int off = 32; off >= 1; off >>= 1) v += __shfl_xor(v, off);
    if (lane == 0) red[wave] = v;
    __syncthreads();
    float s_self = red[0] + red[1] + red[2] + red[3];

    for (int l = wave; l < LL; l += 4) {
        float v2 = 0.f;
#pragma unroll
        for (int q = 0; q < 4; ++q) {
            int i = lane + 64 * q;
            v2 += act[((size_t)b * LL + l) * FP + i] * mAw[FP + i];
        }
#pragma unroll
        for (int off = 32; off >= 1; off >>= 1) v2 += __shfl_xor(v2, off);
        if (lane == 0) S2[l] = v2;
    }
    __syncthreads();

    if (t < LL) {
        float s = fmaxf(s_self + S2[t] + mAb[0], 0.f);
        if (mask[b * LL + t] == 0.f) s += -9e8f;
        S2[t] = s;
    }
    __syncthreads();

    float m = -1e30f;
    for (int l = 0; l < LL; ++l) m = fmaxf(m, S2[l]);
    float den = 0.f;
    for (int l = 0; l < LL; ++l) den += expf(S2[l] - m);
    if (t < LL) {
        float w = expf(S2[t] - m) / den * mask[b * LL + t];
        mw[t] = w;
        o_mawv[(size_t)step * (BB * LL) + b * LL + t] = w;
    }
    __syncthreads();

    float acc = 0.f;
    for (int l = 0; l < LL; ++l) acc += mw[l] * AV[((size_t)b * LL + l) * FP + t];
    cx[t] = fmaxf(acc, 0.f);
    __syncthreads();

    float air = mbih[t], aiz = mbih[FP + t], ain = mbih[2 * FP + t];
    float ahr = mbhh[t], ahz = mbhh[FP + t], ahn = mbhh[2 * FP + t];
    for (int i = 0; i < FP; ++i) {
        float c = cx[i], h = hh[i];
        air += c * MihT[i * 768 + t];
        aiz += c * MihT[i * 768 + FP + t];
        ain += c * MihT[i * 768 + 2 * FP + t];
        ahr += h * MhhT[i * 768 + t];
        ahz += h * MhhT[i * 768 + FP + t];
        ahn += h * MhhT[i * 768 + 2 * FP + t];
    }
    float r = 1.f / (1.f + expf(-(air + ahr)));
    float z = 1.f / (1.f + expf(-(aiz + ahz)));
    float n = tanhf(ain + r * ahn);
    float hn = (1.f - z) * n + z * hprev;

    molF[b * FP + t] = hn;
    o_unb[(size_t)(step + 1) * (BB * FP) + b * FP + t] = hn;
    o_mfv[(size_t)(step + 1) * (BB * FP) + b * FP + t] = fmaxf(hn, 0.f);
    if (step == TT - 1) o_molfeat[b * FP + t] = hn;
}

extern "C" void kernel_launch(void* const* d_in, const int* in_sizes, int n_in,
                              void* d_out, int out_size, void* d_ws, size_t ws_size,
                              hipStream_t stream) {
    const float* atom_list = (const float*)d_in[0];
    const float* bond_list = (const float*)d_in[1];
    const int*   adeg      = (const int*)d_in[2];
    const int*   bdeg      = (const int*)d_in[3];
    const float* amask     = (const float*)d_in[4];
    const float* atom_fc_W = (const float*)d_in[5];
    const float* atom_fc_b = (const float*)d_in[6];
    const float* nfc_W     = (const float*)d_in[7];
    const float* nfc_b     = (const float*)d_in[8];
    const float* gwih      = (const float*)d_in[9];
    const float* gwhh      = (const float*)d_in[10];
    const float* gbih      = (const float*)d_in[11];
    const float* gbhh      = (const float*)d_in[12];
    const float* alW       = (const float*)d_in[13];
    const float* alb       = (const float*)d_in[14];
    const float* atW       = (const float*)d_in[15];
    const float* atb       = (const float*)d_in[16];
    const float* mgwih     = (const float*)d_in[17];
    const float* mgwhh     = (const float*)d_in[18];
    const float* mgbih     = (const float*)d_in[19];
    const float* mgbhh     = (const float*)d_in[20];
    const float* malW      = (const float*)d_in[21];
    const float* malb      = (const float*)d_in[22];
    const float* matW      = (const float*)d_in[23];
    const float* matb      = (const float*)d_in[24];

    const size_t BLF = (size_t)BB * LL * FP;
    float* out = (float*)d_out;
    float* O0 = out;                                 // atom_feature / h (fp32)
    float* O1 = out + BLF;                           // afv (4,B,L,FP)
    float* O2 = O1 + 4 * BLF;                        // awv (3,B,L,K)
    float* O3 = O2 + (size_t)RR * BB * LL * KK;      // mfv
    float* O4 = O3 + (size_t)(TT + 1) * BB * FP;     // mol_unb
    float* O5 = O4 + (size_t)(TT + 1) * BB * FP;     // mawv
    float* O6 = O5 + (size_t)TT * BB * LL;           // mol_feature

    // ws layout
    float* ws = (float*)d_ws;
    short* XB   = (short*)ws;                        // BLF shorts: wn bf16
    short* XB2  = XB + BLF;                          // BLF shorts: ctx bf16
    short* HBb  = XB + 2 * BLF;                      // BLF shorts: h bf16
    short* ACTB = XB + 3 * BLF;                      // BLF shorts: relu(h) bf16
    float* AV   = ws;                                // BLF floats, aliases XB+XB2 (mol phase)
    float* rest = ws + 2 * BLF;
    short* ApreB = (short*)rest;                     // BLF shorts
    float* SW    = rest + BLF / 2;                   // B*L floats
    float* MOLF  = SW + (size_t)BB * LL;
    float* WafcT = MOLF + (size_t)BB * FP;
    float* WnT   = WafcT + AA * FP;
    float* MWaT  = WnT + (AA + BDD) * FP;
    float* MihT  = MWaT + (size_t)FP * FP;
    float* MhhT  = MihT + (size_t)FP * 768;
    short* GW    = (short*)(MhhT + (size_t)FP * 768);   // RR*2*(8*48*512) shorts
    short* WaF   = GW + (size_t)RR * 2 * 8 * 48 * 512;  // RR*(8*16*512) shorts
    (void)ws_size; (void)in_sizes; (void)n_in; (void)out_size;

    auto tr = [&](const float* src, float* dst, int O, int I) {
        int n = O * I;
        k_transpose<<<(n + 255) / 256, 256, 0, stream>>>(src, dst, O, I);
    };
    tr(atom_fc_W, WafcT, FP, AA);
    tr(nfc_W, WnT, FP, AA + BDD);
    tr(matW, MWaT, FP, FP);
    tr(mgwih, MihT, 768, FP);
    tr(mgwhh, MhhT, 768, FP);

    const size_t wblk = (size_t)8 * 48 * 512;
    const size_t ablk = (size_t)8 * 16 * 512;
    for (int d = 0; d < RR; ++d) {
        k_prep_frag<<<(int)(wblk + 255) / 256, 256, 0, stream>>>(gwih + (size_t)d * 768 * FP, GW + (size_t)(d * 2 + 0) * wblk, 48);
        k_prep_frag<<<(int)(wblk + 255) / 256, 256, 0, stream>>>(gwhh + (size_t)d * 768 * FP, GW + (size_t)(d * 2 + 1) * wblk, 48);
        k_prep_frag<<<(int)(ablk + 255) / 256, 256, 0, stream>>>(atW + (size_t)d * FP * FP, WaF + (size_t)d * ablk, 16);
    }

    k_atom_fc8<<<BB * LL / 8, 256, 0, stream>>>(atom_list, WafcT, atom_fc_b, O1, O0, HBb);
    k_apre<<<BB * LL / 8, 256, 0, stream>>>(atom_list, WnT, nfc_b, ApreB);

    for (int d = 0; d < RR; ++d) {
        // self-dot source: round 0 h==relu(h) so HBb works; later rounds use ACTB
        const short* selfB = (d == 0) ? HBb : ACTB;
        if (d == 0) {
            k_awn2<1><<<BB, 1024, 0, stream>>>(selfB, ApreB, bond_list, adeg, bdeg,
                    WnT, alW, alb,
                    XB, SW, O2);
        } else {
            k_awn2<0><<<BB, 1024, 0, stream>>>(selfB, ACTB, bond_list, adeg, bdeg,
                    WnT, alW + (size_t)d * 2 * FP, alb + d,
                    XB, SW, O2 + (size_t)d * BB * LL * KK);
        }
        k_ctx_mfma<<<BB * LL / 32, 512, 0, stream>>>(XB, SW, WaF + (size_t)d * ablk,
                atb + (size_t)d * FP, XB2);
        k_gru_mfma<<<BB * LL / 32, 512, 0, stream>>>(XB2, HBb, O0,
                GW + (size_t)(d * 2 + 0) * wblk, GW + (size_t)(d * 2 + 1) * wblk,
                gbih + (size_t)d * 768, gbhh + (size_t)d * 768,
                O1 + (size_t)(d + 1) * BLF, HBb, ACTB);
    }

    const float* actFin = O1 + (size_t)RR * BLF;
    k_mol_reduce<<<BB, 256, 0, stream>>>(O0, actFin, amask, O4, O3, MOLF);
    k_av<<<BB * LL / 8, 256, 0, stream>>>(actFin, MWaT, matb, AV);
    for (int st = 0; st < TT; ++st) {
        k_mol_step<<<BB, 256, 0, stream>>>(st, actFin, AV, MOLF, amask,
                malW, malb, MihT, MhhT, mgbih, mgbhh,
                O3, O4, O5, O6);
    }
}